// Round 1
// baseline (3500.127 us; speedup 1.0000x reference)
//
#include <hip/hip_runtime.h>
#include <math.h>
#include <stdint.h>

#define B_SZ   1024
#define N_TRAIN 100000
#define D_DIM  256
#define NN     128
#define BM 64
#define BN 64
#define BK 32

// ---------------- K0: squared row norms (one wave per row) ----------------
__global__ __launch_bounds__(256) void k0_norms(const float* __restrict__ trainX,
                                                const float* __restrict__ x,
                                                float* __restrict__ tt,
                                                float* __restrict__ xx) {
    int wave = (blockIdx.x * blockDim.x + threadIdx.x) >> 6;
    int lane = threadIdx.x & 63;
    if (wave >= N_TRAIN + B_SZ) return;
    const float* row = (wave < N_TRAIN) ? (trainX + (size_t)wave * D_DIM)
                                        : (x + (size_t)(wave - N_TRAIN) * D_DIM);
    float4 v = ((const float4*)row)[lane];          // 64 lanes * 4 = 256 dims
    float s = v.x*v.x + v.y*v.y + v.z*v.z + v.w*v.w;
    for (int off = 32; off; off >>= 1) s += __shfl_down(s, off, 64);
    if (lane == 0) { if (wave < N_TRAIN) tt[wave] = s; else xx[wave - N_TRAIN] = s; }
}

// ---------------- K1: fp32 GEMM -> squared distances ----------------
// sq[i][j] = xx[i] + tt[j] - 2 * dot(x_i, t_j), clamped >= 0
__global__ __launch_bounds__(256) void k1_dist(const float* __restrict__ x,
                                               const float* __restrict__ trainX,
                                               const float* __restrict__ xx,
                                               const float* __restrict__ tt,
                                               float* __restrict__ dist,
                                               int row0, int nrows) {
    __shared__ __align__(16) float As[BK][BM + 4];   // transposed: [k][m]
    __shared__ __align__(16) float Bs[BK][BN + 4];   // transposed: [k][n]
    const int tx = threadIdx.x & 15, ty = threadIdx.x >> 4;
    const int jb = blockIdx.x * BN;
    const int ib = blockIdx.y * BM;
    float acc[4][4] = {};
    for (int k0 = 0; k0 < D_DIM; k0 += BK) {
        for (int t = threadIdx.x; t < 512; t += 256) {
            int r = t >> 3, kc = (t & 7) << 2;
            float4 v = make_float4(0.f, 0.f, 0.f, 0.f);
            if (ib + r < nrows)
                v = *(const float4*)(x + (size_t)(row0 + ib + r) * D_DIM + k0 + kc);
            As[kc+0][r] = v.x; As[kc+1][r] = v.y; As[kc+2][r] = v.z; As[kc+3][r] = v.w;
        }
        for (int t = threadIdx.x; t < 512; t += 256) {
            int r = t >> 3, kc = (t & 7) << 2;
            float4 v = make_float4(0.f, 0.f, 0.f, 0.f);
            if (jb + r < N_TRAIN)
                v = *(const float4*)(trainX + (size_t)(jb + r) * D_DIM + k0 + kc);
            Bs[kc+0][r] = v.x; Bs[kc+1][r] = v.y; Bs[kc+2][r] = v.z; Bs[kc+3][r] = v.w;
        }
        __syncthreads();
        #pragma unroll
        for (int kk = 0; kk < BK; ++kk) {
            float4 a = *(const float4*)&As[kk][ty * 4];
            float4 b = *(const float4*)&Bs[kk][tx * 4];
            float aa[4] = {a.x, a.y, a.z, a.w};
            float bb[4] = {b.x, b.y, b.z, b.w};
            #pragma unroll
            for (int u = 0; u < 4; ++u)
                #pragma unroll
                for (int v = 0; v < 4; ++v)
                    acc[u][v] = fmaf(aa[u], bb[v], acc[u][v]);
        }
        __syncthreads();
    }
    #pragma unroll
    for (int u = 0; u < 4; ++u) {
        int i = ib + ty * 4 + u;
        if (i >= nrows) continue;
        float xi = xx[row0 + i];
        #pragma unroll
        for (int v = 0; v < 4; ++v) {
            int j = jb + tx * 4 + v;
            if (j >= N_TRAIN) continue;
            float sq = xi + tt[j] - 2.0f * acc[u][v];
            dist[(size_t)i * N_TRAIN + j] = fmaxf(sq, 0.0f);
        }
    }
}

// ---------------- K2: exact top-128 smallest per row (radix select) ----------------
__global__ __launch_bounds__(256) void k2_select(const float* __restrict__ dist, int row0,
                                                 int* __restrict__ nidx,
                                                 float* __restrict__ nsq) {
    const int tid = threadIdx.x;
    const float* row = dist + (size_t)blockIdx.x * N_TRAIN;
    __shared__ int hist[2048];
    __shared__ int s_sel, s_newk;
    __shared__ int wsum[4];
    __shared__ int s_cntA, s_cntT;
    __shared__ unsigned lsVal[NN];
    __shared__ int lsIdx[NN];
    __shared__ int tIdx[NN];
    __shared__ unsigned long long keys[NN];

    unsigned prefix = 0u, mask = 0u;
    int krem = NN;
    const int shifts[3] = {21, 10, 0};
    const int nbits[3]  = {11, 11, 10};

    for (int p = 0; p < 3; ++p) {
        const int nb = 1 << nbits[p];
        const int shift = shifts[p];
        for (int i = tid; i < nb; i += 256) hist[i] = 0;
        __syncthreads();
        for (int j = tid; j < N_TRAIN; j += 256) {
            unsigned u = __float_as_uint(row[j]);      // values >= +0 -> monotone
            if ((u & mask) == prefix)
                atomicAdd(&hist[(u >> shift) & (nb - 1)], 1);
        }
        __syncthreads();
        const int per = nb >> 8;                       // 8 or 4 buckets/thread
        int psum = 0;
        for (int q = 0; q < per; ++q) psum += hist[tid * per + q];
        int incl = psum;
        for (int off = 1; off < 64; off <<= 1) {
            int t2 = __shfl_up(incl, off, 64);
            if ((tid & 63) >= off) incl += t2;
        }
        if ((tid & 63) == 63) wsum[tid >> 6] = incl;
        __syncthreads();
        int wbase = 0;
        for (int w = 0; w < (tid >> 6); ++w) wbase += wsum[w];
        int excl = wbase + (incl - psum);
        if (excl < krem && krem <= excl + psum) {      // exactly one thread
            int run = excl;
            for (int q = 0; q < per; ++q) {
                int h = hist[tid * per + q];
                if (run < krem && krem <= run + h) { s_sel = tid * per + q; s_newk = krem - run; break; }
                run += h;
            }
        }
        __syncthreads();
        prefix |= ((unsigned)s_sel) << shift;
        mask   |= ((unsigned)(nb - 1)) << shift;
        krem = s_newk;
        __syncthreads();
    }
    const unsigned u128 = prefix;        // value of the 128th smallest
    const int tiesNeeded = krem;         // copies of u128 inside top-128 (>=1)
    if (tid == 0) { s_cntA = 0; s_cntT = 0; }
    __syncthreads();
    for (int j = tid; j < N_TRAIN; j += 256) {
        unsigned u = __float_as_uint(row[j]);
        if (u < u128) {
            int p = atomicAdd(&s_cntA, 1);            // exactly 128 - tiesNeeded total
            lsVal[p] = u; lsIdx[p] = j;
        } else if (u == u128) {
            int p = atomicAdd(&s_cntT, 1);
            if (p < NN) tIdx[p] = j;
        }
    }
    __syncthreads();
    int cntA = s_cntA;
    int nt = s_cntT < NN ? s_cntT : NN;
    if (tid == 0 && nt > 1) {                         // deterministic tie order (lowest idx)
        for (int i2 = 1; i2 < nt; ++i2) {
            int v = tIdx[i2]; int j2 = i2 - 1;
            while (j2 >= 0 && tIdx[j2] > v) { tIdx[j2 + 1] = tIdx[j2]; --j2; }
            tIdx[j2 + 1] = v;
        }
    }
    __syncthreads();
    if (tid < tiesNeeded) { lsVal[cntA + tid] = u128; lsIdx[cntA + tid] = tIdx[tid]; }
    __syncthreads();
    if (tid < NN) keys[tid] = ((unsigned long long)lsVal[tid] << 32) | (unsigned)lsIdx[tid];
    for (int ks = 2; ks <= NN; ks <<= 1)
        for (int js = ks >> 1; js > 0; js >>= 1) {
            __syncthreads();
            if (tid < NN) {
                int l2 = tid ^ js;
                if (l2 > tid) {
                    unsigned long long a2 = keys[tid], b2 = keys[l2];
                    if ((a2 > b2) == ((tid & ks) == 0)) { keys[tid] = b2; keys[l2] = a2; }
                }
            }
        }
    __syncthreads();
    if (tid < NN) {
        unsigned long long e = keys[tid];
        size_t o = (size_t)(row0 + blockIdx.x) * NN + tid;
        nidx[o] = (int)(e & 0xFFFFFFFFull);
        nsq[o]  = __uint_as_float((unsigned)(e >> 32));
    }
}

// ---------------- K3: per-row kernel matrix + LDL^T solve + outputs ----------------
__global__ __launch_bounds__(256) void k3_solve(
    const float* __restrict__ trainX, const float* __restrict__ trainy,
    const float* __restrict__ noise, const float* __restrict__ tt,
    const int* __restrict__ nidx, const float* __restrict__ nsq,
    const float* __restrict__ lp, const float* __restrict__ ap,
    const float* __restrict__ ymp, float* __restrict__ out) {

    __shared__ float Xs[128][65];       // gathered neighbor dims chunk (row-major)
    __shared__ float A[128][129];       // kernel matrix / LDL factors
    __shared__ int   idxs[NN];
    __shared__ float ttn[NN], cvec[NN], c0v[NN], wvec[NN];
    __shared__ float red[8];

    const int b = blockIdx.x;
    const int tid = threadIdx.x;
    const int tx = tid & 15, ty = tid >> 4;
    const int lane = tid & 63, wv = tid >> 6;

    const float lv = expf(lp[0]);
    const float av = expf(ap[0]);
    const float ymean = ymp[0];
    const float sc = 1.0f / (lv * 16.0f);   // sqrt(D)=16

    if (tid < NN) {
        int ix = nidx[(size_t)b * NN + tid];
        idxs[tid] = ix;
        ttn[tid] = tt[ix];
        float cc = av * expf(-sqrtf(nsq[(size_t)b * NN + tid]) * sc);
        cvec[tid] = cc; c0v[tid] = cc;
    }
    __syncthreads();

    float acc[8][8];
    #pragma unroll
    for (int u = 0; u < 8; ++u)
        #pragma unroll
        for (int v = 0; v < 8; ++v) acc[u][v] = 0.f;

    for (int c = 0; c < 4; ++c) {       // D chunks of 64
        #pragma unroll
        for (int step = 0; step < 8; ++step) {
            int i = wv * 32 + step * 4 + (lane >> 4);
            int kp = (lane & 15) << 2;
            const float* src = trainX + (size_t)idxs[i] * D_DIM + c * 64 + kp;
            float4 v4 = *(const float4*)src;
            Xs[i][kp + 0] = v4.x; Xs[i][kp + 1] = v4.y;
            Xs[i][kp + 2] = v4.z; Xs[i][kp + 3] = v4.w;
        }
        __syncthreads();
        for (int kk = 0; kk < 64; ++kk) {
            float a8[8], b8[8];
            #pragma unroll
            for (int u = 0; u < 8; ++u) a8[u] = Xs[ty * 8 + u][kk];
            #pragma unroll
            for (int v = 0; v < 8; ++v) b8[v] = Xs[tx * 8 + v][kk];
            #pragma unroll
            for (int u = 0; u < 8; ++u)
                #pragma unroll
                for (int v = 0; v < 8; ++v)
                    acc[u][v] = fmaf(a8[u], b8[v], acc[u][v]);
        }
        __syncthreads();
    }

    #pragma unroll
    for (int u = 0; u < 8; ++u) {
        int i = ty * 8 + u;
        #pragma unroll
        for (int v = 0; v < 8; ++v) {
            int j = tx * 8 + v;
            float sq = fmaxf(ttn[i] + ttn[j] - 2.0f * acc[u][v], 0.0f);
            A[i][j] = av * expf(-sqrtf(sq) * sc);
        }
    }
    __syncthreads();

    // LDL^T elimination (full symmetric update, SPD -> no pivoting)
    for (int k = 0; k < 127; ++k) {
        float invd = 1.0f / A[k][k];
        float cj[8];
        int nj = 0;
        for (int j = k + 1 + tx; j < 128; j += 16) cj[nj++] = A[j][k];
        for (int i = k + 1 + ty; i < 128; i += 16) {
            float lik = A[i][k] * invd;
            int jj = 0;
            for (int j = k + 1 + tx; j < 128; j += 16)
                A[i][j] = fmaf(-lik, cj[jj++], A[i][j]);
        }
        __syncthreads();
    }
    // forward: L y = c  (unit diag; L[j][k] = A[j][k]/d_k)
    for (int k = 0; k < 127; ++k) {
        float yk = cvec[k];
        float invd = 1.0f / A[k][k];
        int j = k + 1 + tid;
        if (j < 128) cvec[j] -= A[j][k] * invd * yk;
        __syncthreads();
    }
    // backward: w_k = cvec[k]/d_k; cvec[j<k] -= A[k][j] * w_k  (A[k][j]=A[j][k])
    for (int k = 127; k >= 0; --k) {
        float wk = cvec[k] / A[k][k];
        if (tid == 0) wvec[k] = wk;
        if (tid < k) cvec[tid] -= A[k][tid] * wk;
        __syncthreads();
    }

    float p1 = 0.f, p2 = 0.f;
    if (tid < NN) {
        float w = wvec[tid];
        float nyv = trainy[idxs[tid]] + 0.01f * noise[(size_t)b * NN + tid] - ymean;
        p1 = w * nyv;
        p2 = w * c0v[tid];
    }
    for (int off = 32; off; off >>= 1) {
        p1 += __shfl_down(p1, off, 64);
        p2 += __shfl_down(p2, off, 64);
    }
    if (lane == 0) { red[wv * 2] = p1; red[wv * 2 + 1] = p2; }
    __syncthreads();
    if (tid == 0) {
        out[b]        = (red[0] + red[2] + red[4] + red[6]) + ymean;  // y
        out[B_SZ + b] = av - (red[1] + red[3] + red[5] + red[7]);     // yVar
    }
}

extern "C" void kernel_launch(void* const* d_in, const int* in_sizes, int n_in,
                              void* d_out, int out_size, void* d_ws, size_t ws_size,
                              hipStream_t stream) {
    const float* x      = (const float*)d_in[0];
    const float* trainX = (const float*)d_in[1];
    const float* trainy = (const float*)d_in[2];
    const float* noise  = (const float*)d_in[3];
    const float* lp     = (const float*)d_in[4];
    const float* ap     = (const float*)d_in[5];
    const float* ymp    = (const float*)d_in[6];
    float* out = (float*)d_out;

    char* ws = (char*)d_ws;
    size_t off = 0;
    auto alloc = [&](size_t bytes) {
        void* p = ws + off;
        off = (off + bytes + 255) & ~(size_t)255;
        return p;
    };
    float* tt   = (float*)alloc((size_t)N_TRAIN * 4);
    float* xx   = (float*)alloc((size_t)B_SZ * 4);
    int*   nidb = (int*)  alloc((size_t)B_SZ * NN * 4);
    float* nsqb = (float*)alloc((size_t)B_SZ * NN * 4);
    size_t distBytes = (ws_size > off) ? (ws_size - off) : 0;
    float* dist = (float*)(ws + off);
    int R = (int)(distBytes / ((size_t)N_TRAIN * 4));
    if (R > B_SZ) R = B_SZ;
    if (R < 1) R = 1;

    {
        int waves = N_TRAIN + B_SZ;
        k0_norms<<<(waves + 3) / 4, 256, 0, stream>>>(trainX, x, tt, xx);
    }
    for (int r0 = 0; r0 < B_SZ; r0 += R) {
        int rc = (B_SZ - r0 < R) ? (B_SZ - r0) : R;
        dim3 g1((N_TRAIN + BN - 1) / BN, (rc + BM - 1) / BM);
        k1_dist<<<g1, 256, 0, stream>>>(x, trainX, xx, tt, dist, r0, rc);
        k2_select<<<rc, 256, 0, stream>>>(dist, r0, nidb, nsqb);
    }
    k3_solve<<<B_SZ, 256, 0, stream>>>(trainX, trainy, noise, tt, nidb, nsqb,
                                       lp, ap, ymp, out);
}

// Round 2
// 2713.628 us; speedup vs baseline: 1.2898x; 1.2898x over previous
//
#include <hip/hip_runtime.h>
#include <math.h>
#include <stdint.h>

#define B_SZ    1024
#define N_TRAIN 100000
#define D_DIM   256
#define NN      128
#define BM 128
#define BN 128
#define BK 32

// ---------------- K0: squared row norms (one wave per row) ----------------
__global__ __launch_bounds__(256) void k0_norms(const float* __restrict__ trainX,
                                                const float* __restrict__ x,
                                                float* __restrict__ tt,
                                                float* __restrict__ xx) {
    int wave = (blockIdx.x * blockDim.x + threadIdx.x) >> 6;
    int lane = threadIdx.x & 63;
    if (wave >= N_TRAIN + B_SZ) return;
    const float* row = (wave < N_TRAIN) ? (trainX + (size_t)wave * D_DIM)
                                        : (x + (size_t)(wave - N_TRAIN) * D_DIM);
    float4 v = ((const float4*)row)[lane];          // 64 lanes * 4 = 256 dims
    float s = v.x*v.x + v.y*v.y + v.z*v.z + v.w*v.w;
    for (int off = 32; off; off >>= 1) s += __shfl_down(s, off, 64);
    if (lane == 0) { if (wave < N_TRAIN) tt[wave] = s; else xx[wave - N_TRAIN] = s; }
}

// ---------------- K1: fp32 GEMM -> squared distances (128x128 tile, 8x8 acc) ----
__global__ __launch_bounds__(256, 3) void k1_dist(const float* __restrict__ x,
                                                  const float* __restrict__ trainX,
                                                  const float* __restrict__ xx,
                                                  const float* __restrict__ tt,
                                                  float* __restrict__ dist,
                                                  int row0, int nrows) {
    __shared__ __align__(16) float As[BK][BM + 4];   // [k][m], stride 132
    __shared__ __align__(16) float Bs[BK][BN + 4];
    const int tid = threadIdx.x;
    const int tx = tid & 15, ty = tid >> 4;
    const size_t jb = (size_t)blockIdx.x * BN;
    const int ib = blockIdx.y * BM;
    float acc[8][8] = {};
    for (int k0 = 0; k0 < D_DIM; k0 += BK) {
        #pragma unroll
        for (int s = 0; s < 4; ++s) {
            int idx = tid + s * 256;                 // 0..1023
            int r = idx >> 3, kc = (idx & 7) << 2;
            float4 v = make_float4(0.f, 0.f, 0.f, 0.f);
            if (ib + r < nrows)
                v = *(const float4*)(x + (size_t)(row0 + ib + r) * D_DIM + k0 + kc);
            As[kc+0][r] = v.x; As[kc+1][r] = v.y; As[kc+2][r] = v.z; As[kc+3][r] = v.w;
            float4 w = make_float4(0.f, 0.f, 0.f, 0.f);
            if (jb + r < N_TRAIN)
                w = *(const float4*)(trainX + (jb + r) * D_DIM + k0 + kc);
            Bs[kc+0][r] = w.x; Bs[kc+1][r] = w.y; Bs[kc+2][r] = w.z; Bs[kc+3][r] = w.w;
        }
        __syncthreads();
        #pragma unroll
        for (int kk = 0; kk < BK; ++kk) {
            float4 al = *(const float4*)&As[kk][ty * 4];        // broadcast (4 addr/wave)
            float4 ah = *(const float4*)&As[kk][64 + ty * 4];
            float4 bl = *(const float4*)&Bs[kk][tx * 4];        // 2-way banks: free
            float4 bh = *(const float4*)&Bs[kk][64 + tx * 4];
            float a8[8] = {al.x, al.y, al.z, al.w, ah.x, ah.y, ah.z, ah.w};
            float b8[8] = {bl.x, bl.y, bl.z, bl.w, bh.x, bh.y, bh.z, bh.w};
            #pragma unroll
            for (int u = 0; u < 8; ++u)
                #pragma unroll
                for (int v = 0; v < 8; ++v)
                    acc[u][v] = fmaf(a8[u], b8[v], acc[u][v]);
        }
        __syncthreads();
    }
    #pragma unroll
    for (int u = 0; u < 8; ++u) {
        int il = (u < 4) ? (ty * 4 + u) : (64 + ty * 4 + (u - 4));
        int i = ib + il;
        if (i >= nrows) continue;
        float xi = xx[row0 + i];
        float* drow = dist + (size_t)i * N_TRAIN;
        {
            size_t j0 = jb + tx * 4;
            if (j0 + 4 <= N_TRAIN) {
                float4 t4 = *(const float4*)(tt + j0);
                float4 o;
                o.x = fmaxf(xi + t4.x - 2.0f * acc[u][0], 0.0f);
                o.y = fmaxf(xi + t4.y - 2.0f * acc[u][1], 0.0f);
                o.z = fmaxf(xi + t4.z - 2.0f * acc[u][2], 0.0f);
                o.w = fmaxf(xi + t4.w - 2.0f * acc[u][3], 0.0f);
                *(float4*)(drow + j0) = o;
            }
        }
        {
            size_t j0 = jb + 64 + tx * 4;
            if (j0 + 4 <= N_TRAIN) {
                float4 t4 = *(const float4*)(tt + j0);
                float4 o;
                o.x = fmaxf(xi + t4.x - 2.0f * acc[u][4], 0.0f);
                o.y = fmaxf(xi + t4.y - 2.0f * acc[u][5], 0.0f);
                o.z = fmaxf(xi + t4.z - 2.0f * acc[u][6], 0.0f);
                o.w = fmaxf(xi + t4.w - 2.0f * acc[u][7], 0.0f);
                *(float4*)(drow + j0) = o;
            }
        }
    }
}

// ---------------- K2: exact top-128 smallest per row (radix select) ----------------
__global__ __launch_bounds__(256) void k2_select(const float* __restrict__ dist, int row0,
                                                 int* __restrict__ nidx,
                                                 float* __restrict__ nsq) {
    const int tid = threadIdx.x;
    const float* row = dist + (size_t)blockIdx.x * N_TRAIN;
    __shared__ int hist[2048];
    __shared__ int s_sel, s_newk;
    __shared__ int wsum[4];
    __shared__ int s_cntA, s_cntT;
    __shared__ unsigned lsVal[NN];
    __shared__ int lsIdx[NN];
    __shared__ int tIdx[NN];
    __shared__ unsigned long long keys[NN];

    unsigned prefix = 0u, mask = 0u;
    int krem = NN;
    const int shifts[3] = {21, 10, 0};
    const int nbits[3]  = {11, 11, 10};

    for (int p = 0; p < 3; ++p) {
        const int nb = 1 << nbits[p];
        const int shift = shifts[p];
        for (int i = tid; i < nb; i += 256) hist[i] = 0;
        __syncthreads();
        for (int j = tid; j < N_TRAIN; j += 256) {
            unsigned u = __float_as_uint(row[j]);      // values >= +0 -> monotone
            if ((u & mask) == prefix)
                atomicAdd(&hist[(u >> shift) & (nb - 1)], 1);
        }
        __syncthreads();
        const int per = nb >> 8;                       // 8 or 4 buckets/thread
        int psum = 0;
        for (int q = 0; q < per; ++q) psum += hist[tid * per + q];
        int incl = psum;
        for (int off = 1; off < 64; off <<= 1) {
            int t2 = __shfl_up(incl, off, 64);
            if ((tid & 63) >= off) incl += t2;
        }
        if ((tid & 63) == 63) wsum[tid >> 6] = incl;
        __syncthreads();
        int wbase = 0;
        for (int w = 0; w < (tid >> 6); ++w) wbase += wsum[w];
        int excl = wbase + (incl - psum);
        if (excl < krem && krem <= excl + psum) {      // exactly one thread
            int run = excl;
            for (int q = 0; q < per; ++q) {
                int h = hist[tid * per + q];
                if (run < krem && krem <= run + h) { s_sel = tid * per + q; s_newk = krem - run; break; }
                run += h;
            }
        }
        __syncthreads();
        prefix |= ((unsigned)s_sel) << shift;
        mask   |= ((unsigned)(nb - 1)) << shift;
        krem = s_newk;
        __syncthreads();
    }
    const unsigned u128 = prefix;        // value of the 128th smallest
    const int tiesNeeded = krem;         // copies of u128 inside top-128 (>=1)
    if (tid == 0) { s_cntA = 0; s_cntT = 0; }
    __syncthreads();
    for (int j = tid; j < N_TRAIN; j += 256) {
        unsigned u = __float_as_uint(row[j]);
        if (u < u128) {
            int p = atomicAdd(&s_cntA, 1);            // exactly 128 - tiesNeeded total
            lsVal[p] = u; lsIdx[p] = j;
        } else if (u == u128) {
            int p = atomicAdd(&s_cntT, 1);
            if (p < NN) tIdx[p] = j;
        }
    }
    __syncthreads();
    int cntA = s_cntA;
    int nt = s_cntT < NN ? s_cntT : NN;
    if (tid == 0 && nt > 1) {                         // deterministic tie order (lowest idx)
        for (int i2 = 1; i2 < nt; ++i2) {
            int v = tIdx[i2]; int j2 = i2 - 1;
            while (j2 >= 0 && tIdx[j2] > v) { tIdx[j2 + 1] = tIdx[j2]; --j2; }
            tIdx[j2 + 1] = v;
        }
    }
    __syncthreads();
    if (tid < tiesNeeded) { lsVal[cntA + tid] = u128; lsIdx[cntA + tid] = tIdx[tid]; }
    __syncthreads();
    if (tid < NN) keys[tid] = ((unsigned long long)lsVal[tid] << 32) | (unsigned)lsIdx[tid];
    for (int ks = 2; ks <= NN; ks <<= 1)
        for (int js = ks >> 1; js > 0; js >>= 1) {
            __syncthreads();
            if (tid < NN) {
                int l2 = tid ^ js;
                if (l2 > tid) {
                    unsigned long long a2 = keys[tid], b2 = keys[l2];
                    if ((a2 > b2) == ((tid & ks) == 0)) { keys[tid] = b2; keys[l2] = a2; }
                }
            }
        }
    __syncthreads();
    if (tid < NN) {
        unsigned long long e = keys[tid];
        size_t o = (size_t)(row0 + blockIdx.x) * NN + tid;
        nidx[o] = (int)(e & 0xFFFFFFFFull);
        nsq[o]  = __uint_as_float((unsigned)(e >> 32));
    }
}

// ---------------- K3: per-row kernel matrix + LDL^T solve + outputs ----------------
// LDS: A[128][129] fp32 (Xs aliased inside it during the GEMM phase) -> ~68 KB -> 2 blocks/CU
__global__ __launch_bounds__(256, 2) void k3_solve(
    const float* __restrict__ trainX, const float* __restrict__ trainy,
    const float* __restrict__ noise, const float* __restrict__ tt,
    const int* __restrict__ nidx, const float* __restrict__ nsq,
    const float* __restrict__ lp, const float* __restrict__ ap,
    const float* __restrict__ ymp, float* __restrict__ out) {

    __shared__ __align__(16) float Abase[128 * 129];  // A(i,j) = Abase[i*129+j]; col 128 = rhs
    __shared__ int   idxs[NN];
    __shared__ float ttn[NN], c0v[NN], wvec[NN];
    __shared__ float red[8];
    float* Xs = Abase;                                // alias: Xs(i,kk) = Xs[i*65+kk] (8320 floats)

    const int b = blockIdx.x;
    const int tid = threadIdx.x;
    const int tx = tid & 15, ty = tid >> 4;
    const int lane = tid & 63, wv = tid >> 6;

    const float lv = expf(lp[0]);
    const float av = expf(ap[0]);
    const float ymean = ymp[0];
    const float sc = 1.0f / (lv * 16.0f);   // sqrt(D)=16

    if (tid < NN) {
        int ix = nidx[(size_t)b * NN + tid];
        idxs[tid] = ix;
        ttn[tid] = tt[ix];
        c0v[tid] = av * expf(-sqrtf(nsq[(size_t)b * NN + tid]) * sc);
    }
    __syncthreads();

    float acc[8][8];
    #pragma unroll
    for (int u = 0; u < 8; ++u)
        #pragma unroll
        for (int v = 0; v < 8; ++v) acc[u][v] = 0.f;

    for (int c = 0; c < 4; ++c) {       // D chunks of 64, staged in aliased Xs
        #pragma unroll
        for (int s = 0; s < 8; ++s) {
            int idx = tid + s * 256;    // 0..2047
            int i = idx >> 4, kp = (idx & 15) << 2;
            const float* src = trainX + (size_t)idxs[i] * D_DIM + c * 64 + kp;
            float4 v4 = *(const float4*)src;
            Xs[i * 65 + kp + 0] = v4.x; Xs[i * 65 + kp + 1] = v4.y;
            Xs[i * 65 + kp + 2] = v4.z; Xs[i * 65 + kp + 3] = v4.w;
        }
        __syncthreads();
        for (int kk = 0; kk < 64; ++kk) {
            float a8[8], b8[8];
            #pragma unroll
            for (int r = 0; r < 4; ++r) {
                a8[r]     = Xs[(ty * 4 + r) * 65 + kk];        // broadcast within wave
                a8[4 + r] = Xs[(64 + ty * 4 + r) * 65 + kk];
                b8[r]     = Xs[(tx * 4 + r) * 65 + kk];        // 2-way banks: free
                b8[4 + r] = Xs[(64 + tx * 4 + r) * 65 + kk];
            }
            #pragma unroll
            for (int u = 0; u < 8; ++u)
                #pragma unroll
                for (int v = 0; v < 8; ++v)
                    acc[u][v] = fmaf(a8[u], b8[v], acc[u][v]);
        }
        __syncthreads();
    }

    // write kernel matrix (overwrites Xs alias region; acc fully in registers)
    #pragma unroll
    for (int u = 0; u < 8; ++u) {
        int i = (u < 4) ? (ty * 4 + u) : (64 + ty * 4 + (u - 4));
        float ti = ttn[i];
        #pragma unroll
        for (int v = 0; v < 8; ++v) {
            int j = (v < 4) ? (tx * 4 + v) : (64 + tx * 4 + (v - 4));
            float sq = fmaxf(ti + ttn[j] - 2.0f * acc[u][v], 0.0f);
            Abase[i * 129 + j] = av * expf(-sqrtf(sq) * sc);
        }
    }
    if (tid < NN) Abase[tid * 129 + 128] = c0v[tid];   // augmented rhs column
    __syncthreads();

    // LDL^T elimination with fused forward substitution (augmented col 128).
    // Fully static indexing; predicated slots (trailing block shrinks with k).
    for (int k = 0; k < 127; ++k) {
        float invd = 1.0f / Abase[k * 129 + k];
        float ck = Abase[k * 129 + 128];
        float cj[8], lik[8];
        #pragma unroll
        for (int q = 0; q < 8; ++q) {
            int j = tx + q * 16;
            cj[q] = (j > k) ? Abase[j * 129 + k] : 0.f;    // symmetry: A(k,j)=A(j,k)
        }
        #pragma unroll
        for (int p = 0; p < 8; ++p) {
            int i = ty + p * 16;
            lik[p] = (i > k) ? Abase[i * 129 + k] * invd : 0.f;
        }
        #pragma unroll
        for (int p = 0; p < 8; ++p) {
            int i = ty + p * 16;
            if (i > k) {
                float l = lik[p];
                #pragma unroll
                for (int q = 0; q < 8; ++q) {
                    int j = tx + q * 16;
                    if (j > k)
                        Abase[i * 129 + j] = fmaf(-l, cj[q], Abase[i * 129 + j]);
                }
                if (tx == 0)
                    Abase[i * 129 + 128] = fmaf(-l, ck, Abase[i * 129 + 128]);
            }
        }
        __syncthreads();
    }

    // backward: w_k = y_k / d_k;  y_j -= A(k,j) * w_k  (j < k), using row-k reads
    for (int k = 127; k >= 0; --k) {
        float wk = Abase[k * 129 + 128] / Abase[k * 129 + k];
        if (tid == 0) wvec[k] = wk;
        if (tid < k)
            Abase[tid * 129 + 128] = fmaf(-Abase[k * 129 + tid], wk, Abase[tid * 129 + 128]);
        __syncthreads();
    }

    float p1 = 0.f, p2 = 0.f;
    if (tid < NN) {
        float w = wvec[tid];
        float nyv = trainy[idxs[tid]] + 0.01f * noise[(size_t)b * NN + tid] - ymean;
        p1 = w * nyv;
        p2 = w * c0v[tid];
    }
    for (int off = 32; off; off >>= 1) {
        p1 += __shfl_down(p1, off, 64);
        p2 += __shfl_down(p2, off, 64);
    }
    if (lane == 0) { red[wv * 2] = p1; red[wv * 2 + 1] = p2; }
    __syncthreads();
    if (tid == 0) {
        out[b]        = (red[0] + red[2] + red[4] + red[6]) + ymean;  // y
        out[B_SZ + b] = av - (red[1] + red[3] + red[5] + red[7]);     // yVar
    }
}

extern "C" void kernel_launch(void* const* d_in, const int* in_sizes, int n_in,
                              void* d_out, int out_size, void* d_ws, size_t ws_size,
                              hipStream_t stream) {
    const float* x      = (const float*)d_in[0];
    const float* trainX = (const float*)d_in[1];
    const float* trainy = (const float*)d_in[2];
    const float* noise  = (const float*)d_in[3];
    const float* lp     = (const float*)d_in[4];
    const float* ap     = (const float*)d_in[5];
    const float* ymp    = (const float*)d_in[6];
    float* out = (float*)d_out;

    char* ws = (char*)d_ws;
    size_t off = 0;
    auto alloc = [&](size_t bytes) {
        void* p = ws + off;
        off = (off + bytes + 255) & ~(size_t)255;
        return p;
    };
    float* tt   = (float*)alloc((size_t)N_TRAIN * 4);
    float* xx   = (float*)alloc((size_t)B_SZ * 4);
    int*   nidb = (int*)  alloc((size_t)B_SZ * NN * 4);
    float* nsqb = (float*)alloc((size_t)B_SZ * NN * 4);
    size_t distBytes = (ws_size > off) ? (ws_size - off) : 0;
    float* dist = (float*)(ws + off);
    int R = (int)(distBytes / ((size_t)N_TRAIN * 4));
    if (R > B_SZ) R = B_SZ;
    if (R < 1) R = 1;

    {
        int waves = N_TRAIN + B_SZ;
        k0_norms<<<(waves + 3) / 4, 256, 0, stream>>>(trainX, x, tt, xx);
    }
    for (int r0 = 0; r0 < B_SZ; r0 += R) {
        int rc = (B_SZ - r0 < R) ? (B_SZ - r0) : R;
        dim3 g1((N_TRAIN + BN - 1) / BN, (rc + BM - 1) / BM);
        k1_dist<<<g1, 256, 0, stream>>>(x, trainX, xx, tt, dist, r0, rc);
        k2_select<<<rc, 256, 0, stream>>>(dist, r0, nidb, nsqb);
    }
    k3_solve<<<B_SZ, 256, 0, stream>>>(trainX, trainy, noise, tt, nidb, nsqb,
                                       lp, ap, ymp, out);
}

// Round 3
// 2267.371 us; speedup vs baseline: 1.5437x; 1.1968x over previous
//
#include <hip/hip_runtime.h>
#include <math.h>
#include <stdint.h>

#define B_SZ    1024
#define N_TRAIN 100000
#define N_HALF  50000
#define D_DIM   256
#define NN      128
#define BM 128
#define BN 128
#define BK 32

// ---------------- K0: squared row norms (one wave per row) ----------------
__global__ __launch_bounds__(256) void k0_norms(const float* __restrict__ trainX,
                                                const float* __restrict__ x,
                                                float* __restrict__ tt,
                                                float* __restrict__ xx) {
    int wave = (blockIdx.x * blockDim.x + threadIdx.x) >> 6;
    int lane = threadIdx.x & 63;
    if (wave >= N_TRAIN + B_SZ) return;
    const float* row = (wave < N_TRAIN) ? (trainX + (size_t)wave * D_DIM)
                                        : (x + (size_t)(wave - N_TRAIN) * D_DIM);
    float4 v = ((const float4*)row)[lane];          // 64 lanes * 4 = 256 dims
    float s = v.x*v.x + v.y*v.y + v.z*v.z + v.w*v.w;
    for (int off = 32; off; off >>= 1) s += __shfl_down(s, off, 64);
    if (lane == 0) { if (wave < N_TRAIN) tt[wave] = s; else xx[wave - N_TRAIN] = s; }
}

// ---------------- K1: fp32 GEMM -> squared distances (128x128 tile, 8x8 acc) ----
__global__ __launch_bounds__(256, 3) void k1_dist(const float* __restrict__ x,
                                                  const float* __restrict__ trainX,
                                                  const float* __restrict__ xx,
                                                  const float* __restrict__ tt,
                                                  float* __restrict__ dist,
                                                  int row0, int nrows) {
    __shared__ __align__(16) float As[BK][BM + 4];   // [k][m], stride 132
    __shared__ __align__(16) float Bs[BK][BN + 4];
    const int tid = threadIdx.x;
    const int tx = tid & 15, ty = tid >> 4;
    const size_t jb = (size_t)blockIdx.x * BN;
    const int ib = blockIdx.y * BM;
    float acc[8][8] = {};
    for (int k0 = 0; k0 < D_DIM; k0 += BK) {
        #pragma unroll
        for (int s = 0; s < 4; ++s) {
            int idx = tid + s * 256;                 // 0..1023
            int r = idx >> 3, kc = (idx & 7) << 2;
            float4 v = make_float4(0.f, 0.f, 0.f, 0.f);
            if (ib + r < nrows)
                v = *(const float4*)(x + (size_t)(row0 + ib + r) * D_DIM + k0 + kc);
            As[kc+0][r] = v.x; As[kc+1][r] = v.y; As[kc+2][r] = v.z; As[kc+3][r] = v.w;
            float4 w = make_float4(0.f, 0.f, 0.f, 0.f);
            if (jb + r < N_TRAIN)
                w = *(const float4*)(trainX + (jb + r) * D_DIM + k0 + kc);
            Bs[kc+0][r] = w.x; Bs[kc+1][r] = w.y; Bs[kc+2][r] = w.z; Bs[kc+3][r] = w.w;
        }
        __syncthreads();
        #pragma unroll
        for (int kk = 0; kk < BK; ++kk) {
            float4 al = *(const float4*)&As[kk][ty * 4];        // broadcast (4 addr/wave)
            float4 ah = *(const float4*)&As[kk][64 + ty * 4];
            float4 bl = *(const float4*)&Bs[kk][tx * 4];        // 2-way banks: free
            float4 bh = *(const float4*)&Bs[kk][64 + tx * 4];
            float a8[8] = {al.x, al.y, al.z, al.w, ah.x, ah.y, ah.z, ah.w};
            float b8[8] = {bl.x, bl.y, bl.z, bl.w, bh.x, bh.y, bh.z, bh.w};
            #pragma unroll
            for (int u = 0; u < 8; ++u)
                #pragma unroll
                for (int v = 0; v < 8; ++v)
                    acc[u][v] = fmaf(a8[u], b8[v], acc[u][v]);
        }
        __syncthreads();
    }
    #pragma unroll
    for (int u = 0; u < 8; ++u) {
        int il = (u < 4) ? (ty * 4 + u) : (64 + ty * 4 + (u - 4));
        int i = ib + il;
        if (i >= nrows) continue;
        float xi = xx[row0 + i];
        float* drow = dist + (size_t)i * N_TRAIN;
        {
            size_t j0 = jb + tx * 4;
            if (j0 + 4 <= N_TRAIN) {
                float4 t4 = *(const float4*)(tt + j0);
                float4 o;
                o.x = fmaxf(xi + t4.x - 2.0f * acc[u][0], 0.0f);
                o.y = fmaxf(xi + t4.y - 2.0f * acc[u][1], 0.0f);
                o.z = fmaxf(xi + t4.z - 2.0f * acc[u][2], 0.0f);
                o.w = fmaxf(xi + t4.w - 2.0f * acc[u][3], 0.0f);
                *(float4*)(drow + j0) = o;
            }
        }
        {
            size_t j0 = jb + 64 + tx * 4;
            if (j0 + 4 <= N_TRAIN) {
                float4 t4 = *(const float4*)(tt + j0);
                float4 o;
                o.x = fmaxf(xi + t4.x - 2.0f * acc[u][4], 0.0f);
                o.y = fmaxf(xi + t4.y - 2.0f * acc[u][5], 0.0f);
                o.z = fmaxf(xi + t4.z - 2.0f * acc[u][6], 0.0f);
                o.w = fmaxf(xi + t4.w - 2.0f * acc[u][7], 0.0f);
                *(float4*)(drow + j0) = o;
            }
        }
    }
}

// ---------------- K2: exact top-128 smallest per HALF-row (radix select) ---------
// grid = 2 * nrows blocks; block b handles row (b>>1), columns [half*50000, +50000).
// Histogram atomics are wave-aggregated (ballot loop over unique buckets) to kill
// same-address LDS atomic serialization on the concentrated pass-1 digit.
__global__ __launch_bounds__(256) void k2_select(const float* __restrict__ dist, int row0,
                                                 unsigned long long* __restrict__ cand) {
    const int tid = threadIdx.x;
    const int lane = tid & 63;
    const int rloc = blockIdx.x >> 1;
    const int half = blockIdx.x & 1;
    const float4* row4 = (const float4*)(dist + (size_t)rloc * N_TRAIN + (size_t)half * N_HALF);
    const int jbase = half * N_HALF;

    __shared__ int hist[2048];
    __shared__ int s_sel, s_newk;
    __shared__ int wsum[4];
    __shared__ int s_cntA, s_cntT;
    __shared__ unsigned lsVal[NN];
    __shared__ int lsIdx[NN];
    __shared__ int tIdx[NN];

    unsigned prefix = 0u, mask = 0u;
    int krem = NN;
    const int shifts[3] = {21, 10, 0};
    const int nbits[3]  = {11, 11, 10};

    for (int p = 0; p < 3; ++p) {
        const int nb = 1 << nbits[p];
        const int shift = shifts[p];
        for (int i = tid; i < nb; i += 256) hist[i] = 0;
        __syncthreads();
        for (int j4 = tid; j4 < N_HALF / 4; j4 += 256) {
            float4 v4 = row4[j4];
            unsigned uu[4] = {__float_as_uint(v4.x), __float_as_uint(v4.y),
                              __float_as_uint(v4.z), __float_as_uint(v4.w)};
            #pragma unroll
            for (int c = 0; c < 4; ++c) {
                unsigned u = uu[c];
                bool part = ((u & mask) == prefix);
                unsigned d = (u >> shift) & (unsigned)(nb - 1);
                unsigned long long todo = __ballot(part);
                while (todo) {
                    int leader = __ffsll((unsigned long long)todo) - 1;
                    unsigned lb = (unsigned)__shfl((int)d, leader, 64);
                    unsigned long long m = __ballot(part && (d == lb));
                    if (lane == leader) atomicAdd(&hist[lb], (int)__popcll(m));
                    todo &= ~m;
                }
            }
        }
        __syncthreads();
        const int per = nb >> 8;                       // 8 or 4 buckets/thread
        int psum = 0;
        for (int q = 0; q < per; ++q) psum += hist[tid * per + q];
        int incl = psum;
        for (int off = 1; off < 64; off <<= 1) {
            int t2 = __shfl_up(incl, off, 64);
            if ((tid & 63) >= off) incl += t2;
        }
        if ((tid & 63) == 63) wsum[tid >> 6] = incl;
        __syncthreads();
        int wbase = 0;
        for (int w = 0; w < (tid >> 6); ++w) wbase += wsum[w];
        int excl = wbase + (incl - psum);
        if (excl < krem && krem <= excl + psum) {      // exactly one thread
            int run = excl;
            for (int q = 0; q < per; ++q) {
                int h = hist[tid * per + q];
                if (run < krem && krem <= run + h) { s_sel = tid * per + q; s_newk = krem - run; break; }
                run += h;
            }
        }
        __syncthreads();
        prefix |= ((unsigned)s_sel) << shift;
        mask   |= ((unsigned)(nb - 1)) << shift;
        krem = s_newk;
        __syncthreads();
    }
    const unsigned u128 = prefix;        // value of the 128th smallest in this half
    const int tiesNeeded = krem;         // copies of u128 inside top-128 (>=1)
    if (tid == 0) { s_cntA = 0; s_cntT = 0; }
    __syncthreads();
    for (int j4 = tid; j4 < N_HALF / 4; j4 += 256) {
        float4 v4 = row4[j4];
        unsigned uu[4] = {__float_as_uint(v4.x), __float_as_uint(v4.y),
                          __float_as_uint(v4.z), __float_as_uint(v4.w)};
        #pragma unroll
        for (int c = 0; c < 4; ++c) {
            unsigned u = uu[c];
            if (u < u128) {
                int p = atomicAdd(&s_cntA, 1);        // exactly 128 - tiesNeeded total
                lsVal[p] = u; lsIdx[p] = jbase + j4 * 4 + c;
            } else if (u == u128) {
                int p = atomicAdd(&s_cntT, 1);
                if (p < NN) tIdx[p] = jbase + j4 * 4 + c;
            }
        }
    }
    __syncthreads();
    int cntA = s_cntA;
    int nt = s_cntT < NN ? s_cntT : NN;
    if (tid == 0 && nt > 1) {                         // deterministic tie order (lowest idx)
        for (int i2 = 1; i2 < nt; ++i2) {
            int v = tIdx[i2]; int j2 = i2 - 1;
            while (j2 >= 0 && tIdx[j2] > v) { tIdx[j2 + 1] = tIdx[j2]; --j2; }
            tIdx[j2 + 1] = v;
        }
    }
    __syncthreads();
    if (tid < tiesNeeded) { lsVal[cntA + tid] = u128; lsIdx[cntA + tid] = tIdx[tid]; }
    __syncthreads();
    if (tid < NN) {
        size_t o = ((size_t)(row0 + rloc) * 2 + half) * NN + tid;
        cand[o] = ((unsigned long long)lsVal[tid] << 32) | (unsigned)lsIdx[tid];
    }
}

// ---------------- K2b: merge two half-candidates -> exact sorted top-128 ----------
__global__ __launch_bounds__(256) void k2_merge(const unsigned long long* __restrict__ cand,
                                                int* __restrict__ nidx,
                                                float* __restrict__ nsq) {
    __shared__ unsigned long long keys[256];
    const int b = blockIdx.x, tid = threadIdx.x;
    keys[tid] = cand[(size_t)b * 256 + tid];
    for (int ks = 2; ks <= 256; ks <<= 1)
        for (int js = ks >> 1; js > 0; js >>= 1) {
            __syncthreads();
            int l2 = tid ^ js;
            if (l2 > tid) {
                unsigned long long a2 = keys[tid], b2 = keys[l2];
                if ((a2 > b2) == ((tid & ks) == 0)) { keys[tid] = b2; keys[l2] = a2; }
            }
        }
    __syncthreads();
    if (tid < NN) {
        unsigned long long e = keys[tid];
        size_t o = (size_t)b * NN + tid;
        nidx[o] = (int)(e & 0xFFFFFFFFull);
        nsq[o]  = __uint_as_float((unsigned)(e >> 32));
    }
}

// ---------------- K3: per-row kernel matrix + LDL^T solve + outputs ----------------
// LDS: A[128][129] fp32 (Xs aliased inside it during the GEMM phase) -> ~68 KB -> 2 blocks/CU
__global__ __launch_bounds__(256, 2) void k3_solve(
    const float* __restrict__ trainX, const float* __restrict__ trainy,
    const float* __restrict__ noise, const float* __restrict__ tt,
    const int* __restrict__ nidx, const float* __restrict__ nsq,
    const float* __restrict__ lp, const float* __restrict__ ap,
    const float* __restrict__ ymp, float* __restrict__ out) {

    __shared__ __align__(16) float Abase[128 * 129];  // A(i,j) = Abase[i*129+j]; col 128 = rhs
    __shared__ int   idxs[NN];
    __shared__ float ttn[NN], c0v[NN], wvec[NN];
    __shared__ float red[8];
    float* Xs = Abase;                                // alias: Xs(i,kk) = Xs[i*65+kk] (8320 floats)

    const int b = blockIdx.x;
    const int tid = threadIdx.x;
    const int tx = tid & 15, ty = tid >> 4;
    const int lane = tid & 63, wv = tid >> 6;

    const float lv = expf(lp[0]);
    const float av = expf(ap[0]);
    const float ymean = ymp[0];
    const float sc = 1.0f / (lv * 16.0f);   // sqrt(D)=16

    if (tid < NN) {
        int ix = nidx[(size_t)b * NN + tid];
        idxs[tid] = ix;
        ttn[tid] = tt[ix];
        c0v[tid] = av * expf(-sqrtf(nsq[(size_t)b * NN + tid]) * sc);
    }
    __syncthreads();

    float acc[8][8];
    #pragma unroll
    for (int u = 0; u < 8; ++u)
        #pragma unroll
        for (int v = 0; v < 8; ++v) acc[u][v] = 0.f;

    for (int c = 0; c < 4; ++c) {       // D chunks of 64, staged in aliased Xs
        #pragma unroll
        for (int s = 0; s < 8; ++s) {
            int idx = tid + s * 256;    // 0..2047
            int i = idx >> 4, kp = (idx & 15) << 2;
            const float* src = trainX + (size_t)idxs[i] * D_DIM + c * 64 + kp;
            float4 v4 = *(const float4*)src;
            Xs[i * 65 + kp + 0] = v4.x; Xs[i * 65 + kp + 1] = v4.y;
            Xs[i * 65 + kp + 2] = v4.z; Xs[i * 65 + kp + 3] = v4.w;
        }
        __syncthreads();
        for (int kk = 0; kk < 64; ++kk) {
            float a8[8], b8[8];
            #pragma unroll
            for (int r = 0; r < 4; ++r) {
                a8[r]     = Xs[(ty * 4 + r) * 65 + kk];        // broadcast within wave
                a8[4 + r] = Xs[(64 + ty * 4 + r) * 65 + kk];
                b8[r]     = Xs[(tx * 4 + r) * 65 + kk];        // 2-way banks: free
                b8[4 + r] = Xs[(64 + tx * 4 + r) * 65 + kk];
            }
            #pragma unroll
            for (int u = 0; u < 8; ++u)
                #pragma unroll
                for (int v = 0; v < 8; ++v)
                    acc[u][v] = fmaf(a8[u], b8[v], acc[u][v]);
        }
        __syncthreads();
    }

    // write kernel matrix (overwrites Xs alias region; acc fully in registers)
    #pragma unroll
    for (int u = 0; u < 8; ++u) {
        int i = (u < 4) ? (ty * 4 + u) : (64 + ty * 4 + (u - 4));
        float ti = ttn[i];
        #pragma unroll
        for (int v = 0; v < 8; ++v) {
            int j = (v < 4) ? (tx * 4 + v) : (64 + tx * 4 + (v - 4));
            float sq = fmaxf(ti + ttn[j] - 2.0f * acc[u][v], 0.0f);
            Abase[i * 129 + j] = av * expf(-sqrtf(sq) * sc);
        }
    }
    if (tid < NN) Abase[tid * 129 + 128] = c0v[tid];   // augmented rhs column
    __syncthreads();

    // LDL^T elimination with fused forward substitution (augmented col 128).
    // Fully static indexing; predicated slots (trailing block shrinks with k).
    for (int k = 0; k < 127; ++k) {
        float invd = 1.0f / Abase[k * 129 + k];
        float ck = Abase[k * 129 + 128];
        float cj[8], lik[8];
        #pragma unroll
        for (int q = 0; q < 8; ++q) {
            int j = tx + q * 16;
            cj[q] = (j > k) ? Abase[j * 129 + k] : 0.f;    // symmetry: A(k,j)=A(j,k)
        }
        #pragma unroll
        for (int p = 0; p < 8; ++p) {
            int i = ty + p * 16;
            lik[p] = (i > k) ? Abase[i * 129 + k] * invd : 0.f;
        }
        #pragma unroll
        for (int p = 0; p < 8; ++p) {
            int i = ty + p * 16;
            if (i > k) {
                float l = lik[p];
                #pragma unroll
                for (int q = 0; q < 8; ++q) {
                    int j = tx + q * 16;
                    if (j > k)
                        Abase[i * 129 + j] = fmaf(-l, cj[q], Abase[i * 129 + j]);
                }
                if (tx == 0)
                    Abase[i * 129 + 128] = fmaf(-l, ck, Abase[i * 129 + 128]);
            }
        }
        __syncthreads();
    }

    // backward: w_k = y_k / d_k;  y_j -= A(k,j) * w_k  (j < k), using row-k reads
    for (int k = 127; k >= 0; --k) {
        float wk = Abase[k * 129 + 128] / Abase[k * 129 + k];
        if (tid == 0) wvec[k] = wk;
        if (tid < k)
            Abase[tid * 129 + 128] = fmaf(-Abase[k * 129 + tid], wk, Abase[tid * 129 + 128]);
        __syncthreads();
    }

    float p1 = 0.f, p2 = 0.f;
    if (tid < NN) {
        float w = wvec[tid];
        float nyv = trainy[idxs[tid]] + 0.01f * noise[(size_t)b * NN + tid] - ymean;
        p1 = w * nyv;
        p2 = w * c0v[tid];
    }
    for (int off = 32; off; off >>= 1) {
        p1 += __shfl_down(p1, off, 64);
        p2 += __shfl_down(p2, off, 64);
    }
    if (lane == 0) { red[wv * 2] = p1; red[wv * 2 + 1] = p2; }
    __syncthreads();
    if (tid == 0) {
        out[b]        = (red[0] + red[2] + red[4] + red[6]) + ymean;  // y
        out[B_SZ + b] = av - (red[1] + red[3] + red[5] + red[7]);     // yVar
    }
}

extern "C" void kernel_launch(void* const* d_in, const int* in_sizes, int n_in,
                              void* d_out, int out_size, void* d_ws, size_t ws_size,
                              hipStream_t stream) {
    const float* x      = (const float*)d_in[0];
    const float* trainX = (const float*)d_in[1];
    const float* trainy = (const float*)d_in[2];
    const float* noise  = (const float*)d_in[3];
    const float* lp     = (const float*)d_in[4];
    const float* ap     = (const float*)d_in[5];
    const float* ymp    = (const float*)d_in[6];
    float* out = (float*)d_out;

    char* ws = (char*)d_ws;
    size_t off = 0;
    auto alloc = [&](size_t bytes) {
        void* p = ws + off;
        off = (off + bytes + 255) & ~(size_t)255;
        return p;
    };
    float* tt   = (float*)alloc((size_t)N_TRAIN * 4);
    float* xx   = (float*)alloc((size_t)B_SZ * 4);
    int*   nidb = (int*)  alloc((size_t)B_SZ * NN * 4);
    float* nsqb = (float*)alloc((size_t)B_SZ * NN * 4);
    unsigned long long* cand = (unsigned long long*)alloc((size_t)B_SZ * 2 * NN * 8);
    size_t distBytes = (ws_size > off) ? (ws_size - off) : 0;
    float* dist = (float*)(ws + off);
    int R = (int)(distBytes / ((size_t)N_TRAIN * 4));
    if (R > B_SZ) R = B_SZ;
    if (R < 1) R = 1;

    {
        int waves = N_TRAIN + B_SZ;
        k0_norms<<<(waves + 3) / 4, 256, 0, stream>>>(trainX, x, tt, xx);
    }
    for (int r0 = 0; r0 < B_SZ; r0 += R) {
        int rc = (B_SZ - r0 < R) ? (B_SZ - r0) : R;
        dim3 g1((N_TRAIN + BN - 1) / BN, (rc + BM - 1) / BM);
        k1_dist<<<g1, 256, 0, stream>>>(x, trainX, xx, tt, dist, r0, rc);
        k2_select<<<rc * 2, 256, 0, stream>>>(dist, r0, cand);
    }
    k2_merge<<<B_SZ, 256, 0, stream>>>(cand, nidb, nsqb);
    k3_solve<<<B_SZ, 256, 0, stream>>>(trainX, trainy, noise, tt, nidb, nsqb,
                                       lp, ap, ymp, out);
}

// Round 5
// 2012.097 us; speedup vs baseline: 1.7395x; 1.1269x over previous
//
#include <hip/hip_runtime.h>
#include <math.h>
#include <stdint.h>

#define B_SZ    1024
#define N_TRAIN 100000
#define N_HALF  50000
#define D_DIM   256
#define NN      128
#define KSEL    192          // per-half candidate count (margin 64 ranks over 128)

typedef unsigned short u16;
typedef unsigned long long u64;
typedef __attribute__((ext_vector_type(8))) short short8v;
typedef __attribute__((ext_vector_type(4))) float f32x4;

__device__ inline u16 f2bf(float f) {
    unsigned u = __float_as_uint(f);
    return (u16)((u + 0x7FFFu + ((u >> 16) & 1u)) >> 16);
}

// ---------------- K0: squared row norms (one wave per row) ----------------
__global__ __launch_bounds__(256) void k0_norms(const float* __restrict__ trainX,
                                                const float* __restrict__ x,
                                                float* __restrict__ tt,
                                                float* __restrict__ xx) {
    int wave = (blockIdx.x * blockDim.x + threadIdx.x) >> 6;
    int lane = threadIdx.x & 63;
    if (wave >= N_TRAIN + B_SZ) return;
    const float* row = (wave < N_TRAIN) ? (trainX + (size_t)wave * D_DIM)
                                        : (x + (size_t)(wave - N_TRAIN) * D_DIM);
    float4 v = ((const float4*)row)[lane];
    float s = v.x*v.x + v.y*v.y + v.z*v.z + v.w*v.w;
    for (int off = 32; off; off >>= 1) s += __shfl_down(s, off, 64);
    if (lane == 0) { if (wave < N_TRAIN) tt[wave] = s; else xx[wave - N_TRAIN] = s; }
}

// ---------------- Kcv: fp32 -> bf16 conversion (RNE) ----------------
__global__ __launch_bounds__(256) void kcv(const float* __restrict__ src,
                                           u16* __restrict__ dst, int n4) {
    int stride = gridDim.x * 256;
    for (int i = blockIdx.x * 256 + threadIdx.x; i < n4; i += stride) {
        float4 v = ((const float4*)src)[i];
        u64 p = (u64)f2bf(v.x) | ((u64)f2bf(v.y) << 16)
              | ((u64)f2bf(v.z) << 32) | ((u64)f2bf(v.w) << 48);
        ((u64*)dst)[i] = p;
    }
}

// ---------------- K1m: bf16 MFMA GEMM -> approx sq distances (u16 bf16) ---------
// 128x128 tile, 4 waves (2x2 of 64x64), 16x16x32 MFMA, slot-major LDS (no conflicts).
__global__ __launch_bounds__(256) void k1m(const u16* __restrict__ Ah,
                                           const u16* __restrict__ Bh,
                                           const float* __restrict__ xx,
                                           const float* __restrict__ tt,
                                           u16* __restrict__ distu,
                                           int row0, int nrows) {
    __shared__ u16 Als[4][128][8];    // [kslot][row][8 bf16] -> 16B chunks
    __shared__ u16 Bls[4][128][8];
    const int tid = threadIdx.x;
    const int lane = tid & 63, wv = tid >> 6;
    const int wr = wv >> 1, wc = wv & 1;
    const int ib = blockIdx.y * 128;
    const size_t jb = (size_t)blockIdx.x * 128;

    f32x4 acc[4][4];
    #pragma unroll
    for (int m = 0; m < 4; ++m)
        #pragma unroll
        for (int n = 0; n < 4; ++n)
            #pragma unroll
            for (int r = 0; r < 4; ++r) acc[m][n][r] = 0.f;

    for (int k0 = 0; k0 < D_DIM; k0 += 32) {
        #pragma unroll
        for (int r = 0; r < 2; ++r) {
            int c = tid + r * 256;            // 0..511
            int row = c >> 2, ks = c & 3;
            uint4 va = make_uint4(0, 0, 0, 0);
            if (ib + row < nrows)
                va = *(const uint4*)(Ah + (size_t)(row0 + ib + row) * D_DIM + k0 + ks * 8);
            *(uint4*)(&Als[ks][row][0]) = va;
            uint4 vb = make_uint4(0, 0, 0, 0);
            if (jb + row < N_TRAIN)
                vb = *(const uint4*)(Bh + (jb + row) * D_DIM + k0 + ks * 8);
            *(uint4*)(&Bls[ks][row][0]) = vb;
        }
        __syncthreads();
        const int ksl = lane >> 4, li = lane & 15;
        short8v a[4], b[4];
        #pragma unroll
        for (int m = 0; m < 4; ++m)
            a[m] = *(const short8v*)&Als[ksl][wr * 64 + m * 16 + li][0];
        #pragma unroll
        for (int n = 0; n < 4; ++n)
            b[n] = *(const short8v*)&Bls[ksl][wc * 64 + n * 16 + li][0];
        #pragma unroll
        for (int m = 0; m < 4; ++m)
            #pragma unroll
            for (int n = 0; n < 4; ++n)
                acc[m][n] = __builtin_amdgcn_mfma_f32_16x16x32_bf16(a[m], b[n], acc[m][n], 0, 0, 0);
        __syncthreads();
    }
    // epilogue: C row = (lane>>4)*4 + reg, col = lane&15  [guide §3, m89-verified]
    const int li = lane & 15, lh = lane >> 4;
    float ttv[4]; size_t cols[4];
    #pragma unroll
    for (int n = 0; n < 4; ++n) {
        cols[n] = jb + wc * 64 + n * 16 + li;
        ttv[n] = (cols[n] < N_TRAIN) ? tt[cols[n]] : 0.f;
    }
    #pragma unroll
    for (int m = 0; m < 4; ++m)
        #pragma unroll
        for (int r = 0; r < 4; ++r) {
            int rl = ib + wr * 64 + m * 16 + lh * 4 + r;
            if (rl >= nrows) continue;
            float xi = xx[row0 + rl];
            u16* dr = distu + (size_t)rl * N_TRAIN;
            #pragma unroll
            for (int n = 0; n < 4; ++n)
                if (cols[n] < N_TRAIN)
                    dr[cols[n]] = f2bf(fmaxf(xi + ttv[n] - 2.0f * acc[m][n][r], 0.f));
        }
}

// ---------------- shared helper: 512-key bitonic sort, 256 threads ----------------
__device__ inline void bitonic512(u64* a, int tid) {
    for (int ks = 2; ks <= 512; ks <<= 1)
        for (int js = ks >> 1; js > 0; js >>= 1) {
            #pragma unroll
            for (int s = 0; s < 2; ++s) {
                int e = tid + s * 256, p = e ^ js;
                if (p > e) {
                    u64 A = a[e], B = a[p];
                    if ((A > B) == ((e & ks) == 0)) { a[e] = B; a[p] = A; }
                }
            }
            __syncthreads();
        }
}

// ---------------- K2: per-half-row approx top-KSEL (u16 radix, 1 hist pass) ------
// Histogram atomics wave-aggregated: bf16 codes concentrate (~2-3 hot buckets hold
// half the elements) -> plain atomics would serialize 64-way per wave.
__global__ __launch_bounds__(256) void k2_select(const u16* __restrict__ distu, int row0,
                                                 int* __restrict__ cand) {
    const int tid = threadIdx.x;
    const int lane = tid & 63;
    const int rloc = blockIdx.x >> 1, half = blockIdx.x & 1;
    const uint4* row8 = (const uint4*)(distu + (size_t)rloc * N_TRAIN + (size_t)half * N_HALF);
    const int jbase = half * N_HALF;

    __shared__ int hist[8192];
    __shared__ int wsum[4];
    __shared__ int s_sel, s_krem, s_cntA, s_cntT;
    __shared__ int lsIdx[KSEL];
    __shared__ u64 tie[512];

    for (int i = tid; i < 8192; i += 256) hist[i] = 0;
    if (tid == 0) { s_cntA = 0; s_cntT = 0; }
    __syncthreads();

    for (int j8 = tid; j8 < N_HALF / 8; j8 += 256) {
        uint4 v = row8[j8];
        unsigned w[4] = {v.x, v.y, v.z, v.w};
        #pragma unroll
        for (int c = 0; c < 4; ++c) {
            #pragma unroll
            for (int hc = 0; hc < 2; ++hc) {
                unsigned bkt = (hc ? (w[c] >> 16) : (w[c] & 0xFFFFu)) >> 3;
                u64 act = __ballot(1);                 // active lanes this iter
                u64 todo = act;
                while (todo) {
                    int leader = __ffsll(todo) - 1;
                    unsigned lb = (unsigned)__shfl((int)bkt, leader, 64);
                    u64 m = __ballot(bkt == lb) & act;
                    if (lane == leader) atomicAdd(&hist[lb], (int)__popcll(m));
                    todo &= ~m;
                }
            }
        }
    }
    __syncthreads();
    int psum = 0;
    #pragma unroll
    for (int q = 0; q < 32; ++q) psum += hist[tid * 32 + q];
    int incl = psum;
    for (int off = 1; off < 64; off <<= 1) {
        int t2 = __shfl_up(incl, off, 64);
        if ((tid & 63) >= off) incl += t2;
    }
    if ((tid & 63) == 63) wsum[tid >> 6] = incl;
    __syncthreads();
    int wbase = 0;
    for (int w2 = 0; w2 < (tid >> 6); ++w2) wbase += wsum[w2];
    int excl = wbase + incl - psum;
    if (excl < KSEL && KSEL <= excl + psum) {
        int run = excl;
        for (int q = 0; q < 32; ++q) {
            int h = hist[tid * 32 + q];
            if (run < KSEL && KSEL <= run + h) { s_sel = tid * 32 + q; s_krem = KSEL - run; break; }
            run += h;
        }
    }
    __syncthreads();
    const int Bsel = s_sel, krem = s_krem;

    for (int j8 = tid; j8 < N_HALF / 8; j8 += 256) {
        uint4 v = row8[j8];
        unsigned w[4] = {v.x, v.y, v.z, v.w};
        #pragma unroll
        for (int c = 0; c < 4; ++c) {
            #pragma unroll
            for (int hc = 0; hc < 2; ++hc) {
                unsigned key = hc ? (w[c] >> 16) : (w[c] & 0xFFFFu);
                int bkt = (int)(key >> 3);
                int jg = jbase + j8 * 8 + c * 2 + hc;
                if (bkt < Bsel) { int p = atomicAdd(&s_cntA, 1); lsIdx[p] = jg; }
                else if (bkt == Bsel) {
                    int p = atomicAdd(&s_cntT, 1);
                    if (p < 512) tie[p] = ((u64)key << 32) | (unsigned)jg;
                }
            }
        }
    }
    __syncthreads();
    int nt = s_cntT; if (nt > 512) nt = 512;
    for (int i = tid; i < 512; i += 256) if (i >= nt) tie[i] = ~0ull;
    __syncthreads();
    bitonic512(tie, tid);
    if (tid < krem) lsIdx[s_cntA + tid] = (int)(tie[tid] & 0xFFFFFFFFull);
    __syncthreads();
    if (tid < KSEL)
        cand[((size_t)(row0 + rloc)) * (2 * KSEL) + half * KSEL + tid] = lsIdx[tid];
}

// ---------------- K2m: exact fp32 refine of 2*KSEL candidates -> top-128 ---------
__global__ __launch_bounds__(256) void k2m(const float* __restrict__ x,
                                           const float* __restrict__ trainX,
                                           const float* __restrict__ xx,
                                           const float* __restrict__ tt,
                                           const int* __restrict__ cand,
                                           int* __restrict__ nidx,
                                           float* __restrict__ nsq) {
    __shared__ int sIdx[2 * KSEL];
    __shared__ float4 xs4[64];
    __shared__ u64 keys[512];
    const int b = blockIdx.x, tid = threadIdx.x;
    const int lane = tid & 63, wv = tid >> 6;
    for (int i = tid; i < 2 * KSEL; i += 256)            // FIX: 2*KSEL > 256 threads
        sIdx[i] = cand[(size_t)b * (2 * KSEL) + i];
    if (tid < 64) xs4[tid] = ((const float4*)(x + (size_t)b * D_DIM))[tid];
    for (int i = tid; i < 512; i += 256) keys[i] = ~0ull;
    __syncthreads();
    const int ls = lane & 31;
    const float xxb = xx[b];
    for (int it = 0; it < (2 * KSEL) / 8; ++it) {
        int c = it * 8 + wv * 2 + (lane >> 5);
        int j = sIdx[c];
        const float4* tr = (const float4*)(trainX + (size_t)j * D_DIM);
        float4 p1 = tr[ls * 2], p2 = tr[ls * 2 + 1];
        float4 q1 = xs4[ls * 2], q2 = xs4[ls * 2 + 1];
        float d = p1.x*q1.x + p1.y*q1.y + p1.z*q1.z + p1.w*q1.w
                + p2.x*q2.x + p2.y*q2.y + p2.z*q2.z + p2.w*q2.w;
        #pragma unroll
        for (int m = 1; m < 32; m <<= 1) d += __shfl_xor(d, m, 64);
        if (ls == 0) {
            float sq = fmaxf(xxb + tt[j] - 2.0f * d, 0.f);
            keys[c] = ((u64)__float_as_uint(sq) << 32) | (unsigned)j;
        }
    }
    __syncthreads();
    bitonic512(keys, tid);
    if (tid < NN) {
        u64 e = keys[tid];
        nidx[(size_t)b * NN + tid] = (int)(e & 0xFFFFFFFFull);
        nsq[(size_t)b * NN + tid]  = __uint_as_float((unsigned)(e >> 32));
    }
}

// ---------------- K3: per-row kernel matrix + LDL^T solve + outputs ----------------
__global__ __launch_bounds__(256, 2) void k3_solve(
    const float* __restrict__ trainX, const float* __restrict__ trainy,
    const float* __restrict__ noise, const float* __restrict__ tt,
    const int* __restrict__ nidx, const float* __restrict__ nsq,
    const float* __restrict__ lp, const float* __restrict__ ap,
    const float* __restrict__ ymp, float* __restrict__ out) {

    __shared__ __align__(16) float Abase[128 * 129];  // A(i,j) = Abase[i*129+j]; col 128 = rhs
    __shared__ int   idxs[NN];
    __shared__ float ttn[NN], c0v[NN], wvec[NN];
    __shared__ float red[8];
    float* Xs = Abase;                                // alias during GEMM (stride 65)

    const int b = blockIdx.x;
    const int tid = threadIdx.x;
    const int tx = tid & 15, ty = tid >> 4;
    const int lane = tid & 63, wv = tid >> 6;

    const float lv = expf(lp[0]);
    const float av = expf(ap[0]);
    const float ymean = ymp[0];
    const float sc = 1.0f / (lv * 16.0f);   // sqrt(D)=16

    if (tid < NN) {
        int ix = nidx[(size_t)b * NN + tid];
        idxs[tid] = ix;
        ttn[tid] = tt[ix];
        c0v[tid] = av * expf(-sqrtf(nsq[(size_t)b * NN + tid]) * sc);
    }
    __syncthreads();

    float acc[8][8];
    #pragma unroll
    for (int u = 0; u < 8; ++u)
        #pragma unroll
        for (int v = 0; v < 8; ++v) acc[u][v] = 0.f;

    for (int c = 0; c < 4; ++c) {
        #pragma unroll
        for (int s = 0; s < 8; ++s) {
            int idx = tid + s * 256;
            int i = idx >> 4, kp = (idx & 15) << 2;
            const float* src = trainX + (size_t)idxs[i] * D_DIM + c * 64 + kp;
            float4 v4 = *(const float4*)src;
            Xs[i * 65 + kp + 0] = v4.x; Xs[i * 65 + kp + 1] = v4.y;
            Xs[i * 65 + kp + 2] = v4.z; Xs[i * 65 + kp + 3] = v4.w;
        }
        __syncthreads();
        for (int kk = 0; kk < 64; ++kk) {
            float a8[8], b8[8];
            #pragma unroll
            for (int r = 0; r < 4; ++r) {
                a8[r]     = Xs[(ty * 4 + r) * 65 + kk];
                a8[4 + r] = Xs[(64 + ty * 4 + r) * 65 + kk];
                b8[r]     = Xs[(tx * 4 + r) * 65 + kk];
                b8[4 + r] = Xs[(64 + tx * 4 + r) * 65 + kk];
            }
            #pragma unroll
            for (int u = 0; u < 8; ++u)
                #pragma unroll
                for (int v = 0; v < 8; ++v)
                    acc[u][v] = fmaf(a8[u], b8[v], acc[u][v]);
        }
        __syncthreads();
    }

    #pragma unroll
    for (int u = 0; u < 8; ++u) {
        int i = (u < 4) ? (ty * 4 + u) : (64 + ty * 4 + (u - 4));
        float ti = ttn[i];
        #pragma unroll
        for (int v = 0; v < 8; ++v) {
            int j = (v < 4) ? (tx * 4 + v) : (64 + tx * 4 + (v - 4));
            float sq = fmaxf(ti + ttn[j] - 2.0f * acc[u][v], 0.0f);
            Abase[i * 129 + j] = av * expf(-sqrtf(sq) * sc);
        }
    }
    if (tid < NN) Abase[tid * 129 + 128] = c0v[tid];
    __syncthreads();

    // LDL^T elimination with fused forward substitution (augmented col 128)
    for (int k = 0; k < 127; ++k) {
        float invd = 1.0f / Abase[k * 129 + k];
        float ck = Abase[k * 129 + 128];
        float cj[8], lik[8];
        #pragma unroll
        for (int q = 0; q < 8; ++q) {
            int j = tx + q * 16;
            cj[q] = (j > k) ? Abase[j * 129 + k] : 0.f;
        }
        #pragma unroll
        for (int p = 0; p < 8; ++p) {
            int i = ty + p * 16;
            lik[p] = (i > k) ? Abase[i * 129 + k] * invd : 0.f;
        }
        #pragma unroll
        for (int p = 0; p < 8; ++p) {
            int i = ty + p * 16;
            if (i > k) {
                float l = lik[p];
                #pragma unroll
                for (int q = 0; q < 8; ++q) {
                    int j = tx + q * 16;
                    if (j > k)
                        Abase[i * 129 + j] = fmaf(-l, cj[q], Abase[i * 129 + j]);
                }
                if (tx == 0)
                    Abase[i * 129 + 128] = fmaf(-l, ck, Abase[i * 129 + 128]);
            }
        }
        __syncthreads();
    }

    // backward substitution: single wave, 2 rows/lane in registers, no barriers
    if (tid < 64) {
        int l = tid;
        float y0 = Abase[l * 129 + 128];
        float y1 = Abase[(64 + l) * 129 + 128];
        for (int k = 127; k >= 0; --k) {
            float ysrc = (k >= 64) ? y1 : y0;
            float ykv = __shfl(ysrc, k & 63, 64);
            float wk = ykv / Abase[k * 129 + k];
            if (l == 0) wvec[k] = wk;
            if (l < k)      y0 = fmaf(-Abase[k * 129 + l],      wk, y0);
            if (64 + l < k) y1 = fmaf(-Abase[k * 129 + 64 + l], wk, y1);
        }
    }
    __syncthreads();

    float p1 = 0.f, p2 = 0.f;
    if (tid < NN) {
        float w = wvec[tid];
        float nyv = trainy[idxs[tid]] + 0.01f * noise[(size_t)b * NN + tid] - ymean;
        p1 = w * nyv;
        p2 = w * c0v[tid];
    }
    for (int off = 32; off; off >>= 1) {
        p1 += __shfl_down(p1, off, 64);
        p2 += __shfl_down(p2, off, 64);
    }
    if (lane == 0) { red[wv * 2] = p1; red[wv * 2 + 1] = p2; }
    __syncthreads();
    if (tid == 0) {
        out[b]        = (red[0] + red[2] + red[4] + red[6]) + ymean;
        out[B_SZ + b] = av - (red[1] + red[3] + red[5] + red[7]);
    }
}

extern "C" void kernel_launch(void* const* d_in, const int* in_sizes, int n_in,
                              void* d_out, int out_size, void* d_ws, size_t ws_size,
                              hipStream_t stream) {
    const float* x      = (const float*)d_in[0];
    const float* trainX = (const float*)d_in[1];
    const float* trainy = (const float*)d_in[2];
    const float* noise  = (const float*)d_in[3];
    const float* lp     = (const float*)d_in[4];
    const float* ap     = (const float*)d_in[5];
    const float* ymp    = (const float*)d_in[6];
    float* out = (float*)d_out;

    char* ws = (char*)d_ws;
    size_t off = 0;
    auto alloc = [&](size_t bytes) {
        void* p = ws + off;
        off = (off + bytes + 255) & ~(size_t)255;
        return p;
    };
    float* tt   = (float*)alloc((size_t)N_TRAIN * 4);
    float* xx   = (float*)alloc((size_t)B_SZ * 4);
    int*   nidb = (int*)  alloc((size_t)B_SZ * NN * 4);
    float* nsqb = (float*)alloc((size_t)B_SZ * NN * 4);
    int*   cand = (int*)  alloc((size_t)B_SZ * 2 * KSEL * 4);
    u16*   Ah   = (u16*)  alloc((size_t)B_SZ * D_DIM * 2);
    u16*   Bh   = (u16*)  alloc((size_t)N_TRAIN * D_DIM * 2);
    size_t distBytes = (ws_size > off) ? (ws_size - off) : 0;
    u16* distu = (u16*)(ws + off);
    int R = (int)(distBytes / ((size_t)N_TRAIN * 2));
    if (R > 256) R = 256;        // keep dist chunk L3-resident (51 MB)
    if (R < 1) R = 1;

    {
        int waves = N_TRAIN + B_SZ;
        k0_norms<<<(waves + 3) / 4, 256, 0, stream>>>(trainX, x, tt, xx);
    }
    kcv<<<4096, 256, 0, stream>>>(trainX, Bh, N_TRAIN * D_DIM / 4);
    kcv<<<256, 256, 0, stream>>>(x, Ah, B_SZ * D_DIM / 4);

    for (int r0 = 0; r0 < B_SZ; r0 += R) {
        int rc = (B_SZ - r0 < R) ? (B_SZ - r0) : R;
        dim3 g1((N_TRAIN + 127) / 128, (rc + 127) / 128);
        k1m<<<g1, 256, 0, stream>>>(Ah, Bh, xx, tt, distu, r0, rc);
        k2_select<<<rc * 2, 256, 0, stream>>>(distu, r0, cand);
    }
    k2m<<<B_SZ, 256, 0, stream>>>(x, trainX, xx, tt, cand, nidb, nsqb);
    k3_solve<<<B_SZ, 256, 0, stream>>>(trainX, trainy, noise, tt, nidb, nsqb,
                                       lp, ap, ymp, out);
}

// Round 6
// 1779.103 us; speedup vs baseline: 1.9674x; 1.1310x over previous
//
#include <hip/hip_runtime.h>
#include <math.h>
#include <stdint.h>

#define B_SZ    1024
#define N_TRAIN 100000
#define N_HALF  50000
#define D_DIM   256
#define NN      128
#define KSEL    192          // per-half candidate count (margin 64 ranks over 128)

typedef unsigned short u16;
typedef unsigned long long u64;
typedef __attribute__((ext_vector_type(8))) short short8v;
typedef __attribute__((ext_vector_type(4))) float f32x4;

__device__ inline u16 f2bf(float f) {
    unsigned u = __float_as_uint(f);
    return (u16)((u + 0x7FFFu + ((u >> 16) & 1u)) >> 16);
}

// ---------------- K0: squared row norms (one wave per row) ----------------
__global__ __launch_bounds__(256) void k0_norms(const float* __restrict__ trainX,
                                                const float* __restrict__ x,
                                                float* __restrict__ tt,
                                                float* __restrict__ xx) {
    int wave = (blockIdx.x * blockDim.x + threadIdx.x) >> 6;
    int lane = threadIdx.x & 63;
    if (wave >= N_TRAIN + B_SZ) return;
    const float* row = (wave < N_TRAIN) ? (trainX + (size_t)wave * D_DIM)
                                        : (x + (size_t)(wave - N_TRAIN) * D_DIM);
    float4 v = ((const float4*)row)[lane];
    float s = v.x*v.x + v.y*v.y + v.z*v.z + v.w*v.w;
    for (int off = 32; off; off >>= 1) s += __shfl_down(s, off, 64);
    if (lane == 0) { if (wave < N_TRAIN) tt[wave] = s; else xx[wave - N_TRAIN] = s; }
}

// ---------------- Kcv: fp32 -> bf16 conversion (RNE) ----------------
__global__ __launch_bounds__(256) void kcv(const float* __restrict__ src,
                                           u16* __restrict__ dst, int n4) {
    int stride = gridDim.x * 256;
    for (int i = blockIdx.x * 256 + threadIdx.x; i < n4; i += stride) {
        float4 v = ((const float4*)src)[i];
        u64 p = (u64)f2bf(v.x) | ((u64)f2bf(v.y) << 16)
              | ((u64)f2bf(v.z) << 32) | ((u64)f2bf(v.w) << 48);
        ((u64*)dst)[i] = p;
    }
}

// ---------------- K1m: bf16 MFMA GEMM -> approx sq distances (u16 bf16) ---------
__global__ __launch_bounds__(256) void k1m(const u16* __restrict__ Ah,
                                           const u16* __restrict__ Bh,
                                           const float* __restrict__ xx,
                                           const float* __restrict__ tt,
                                           u16* __restrict__ distu,
                                           int row0, int nrows) {
    __shared__ u16 Als[4][128][8];    // [kslot][row][8 bf16] -> 16B chunks
    __shared__ u16 Bls[4][128][8];
    const int tid = threadIdx.x;
    const int lane = tid & 63, wv = tid >> 6;
    const int wr = wv >> 1, wc = wv & 1;
    const int ib = blockIdx.y * 128;
    const size_t jb = (size_t)blockIdx.x * 128;

    f32x4 acc[4][4];
    #pragma unroll
    for (int m = 0; m < 4; ++m)
        #pragma unroll
        for (int n = 0; n < 4; ++n)
            #pragma unroll
            for (int r = 0; r < 4; ++r) acc[m][n][r] = 0.f;

    for (int k0 = 0; k0 < D_DIM; k0 += 32) {
        #pragma unroll
        for (int r = 0; r < 2; ++r) {
            int c = tid + r * 256;            // 0..511
            int row = c >> 2, ks = c & 3;
            uint4 va = make_uint4(0, 0, 0, 0);
            if (ib + row < nrows)
                va = *(const uint4*)(Ah + (size_t)(row0 + ib + row) * D_DIM + k0 + ks * 8);
            *(uint4*)(&Als[ks][row][0]) = va;
            uint4 vb = make_uint4(0, 0, 0, 0);
            if (jb + row < N_TRAIN)
                vb = *(const uint4*)(Bh + (jb + row) * D_DIM + k0 + ks * 8);
            *(uint4*)(&Bls[ks][row][0]) = vb;
        }
        __syncthreads();
        const int ksl = lane >> 4, li = lane & 15;
        short8v a[4], b[4];
        #pragma unroll
        for (int m = 0; m < 4; ++m)
            a[m] = *(const short8v*)&Als[ksl][wr * 64 + m * 16 + li][0];
        #pragma unroll
        for (int n = 0; n < 4; ++n)
            b[n] = *(const short8v*)&Bls[ksl][wc * 64 + n * 16 + li][0];
        #pragma unroll
        for (int m = 0; m < 4; ++m)
            #pragma unroll
            for (int n = 0; n < 4; ++n)
                acc[m][n] = __builtin_amdgcn_mfma_f32_16x16x32_bf16(a[m], b[n], acc[m][n], 0, 0, 0);
        __syncthreads();
    }
    // epilogue: C row = (lane>>4)*4 + reg, col = lane&15  [guide §3, m89-verified]
    const int li = lane & 15, lh = lane >> 4;
    float ttv[4]; size_t cols[4];
    #pragma unroll
    for (int n = 0; n < 4; ++n) {
        cols[n] = jb + wc * 64 + n * 16 + li;
        ttv[n] = (cols[n] < N_TRAIN) ? tt[cols[n]] : 0.f;
    }
    #pragma unroll
    for (int m = 0; m < 4; ++m)
        #pragma unroll
        for (int r = 0; r < 4; ++r) {
            int rl = ib + wr * 64 + m * 16 + lh * 4 + r;
            if (rl >= nrows) continue;
            float xi = xx[row0 + rl];
            u16* dr = distu + (size_t)rl * N_TRAIN;
            #pragma unroll
            for (int n = 0; n < 4; ++n)
                if (cols[n] < N_TRAIN)
                    dr[cols[n]] = f2bf(fmaxf(xi + ttv[n] - 2.0f * acc[m][n][r], 0.f));
        }
}

// ---------------- shared helper: 512-key bitonic sort, 256 threads ----------------
__device__ inline void bitonic512(u64* a, int tid) {
    for (int ks = 2; ks <= 512; ks <<= 1)
        for (int js = ks >> 1; js > 0; js >>= 1) {
            #pragma unroll
            for (int s = 0; s < 2; ++s) {
                int e = tid + s * 256, p = e ^ js;
                if (p > e) {
                    u64 A = a[e], B = a[p];
                    if ((A > B) == ((e & ks) == 0)) { a[e] = B; a[p] = A; }
                }
            }
            __syncthreads();
        }
}

// ---------------- K2: per-half-row approx top-KSEL (u16 radix, 1 hist pass) ------
__global__ __launch_bounds__(256) void k2_select(const u16* __restrict__ distu, int row0,
                                                 int* __restrict__ cand) {
    const int tid = threadIdx.x;
    const int lane = tid & 63;
    const int rloc = blockIdx.x >> 1, half = blockIdx.x & 1;
    const uint4* row8 = (const uint4*)(distu + (size_t)rloc * N_TRAIN + (size_t)half * N_HALF);
    const int jbase = half * N_HALF;

    __shared__ int hist[8192];
    __shared__ int wsum[4];
    __shared__ int s_sel, s_krem, s_cntA, s_cntT;
    __shared__ int lsIdx[KSEL];
    __shared__ u64 tie[512];

    for (int i = tid; i < 8192; i += 256) hist[i] = 0;
    if (tid == 0) { s_cntA = 0; s_cntT = 0; }
    __syncthreads();

    for (int j8 = tid; j8 < N_HALF / 8; j8 += 256) {
        uint4 v = row8[j8];
        unsigned w[4] = {v.x, v.y, v.z, v.w};
        #pragma unroll
        for (int c = 0; c < 4; ++c) {
            #pragma unroll
            for (int hc = 0; hc < 2; ++hc) {
                unsigned bkt = (hc ? (w[c] >> 16) : (w[c] & 0xFFFFu)) >> 3;
                u64 act = __ballot(1);
                u64 todo = act;
                while (todo) {
                    int leader = __ffsll(todo) - 1;
                    unsigned lb = (unsigned)__shfl((int)bkt, leader, 64);
                    u64 m = __ballot(bkt == lb) & act;
                    if (lane == leader) atomicAdd(&hist[lb], (int)__popcll(m));
                    todo &= ~m;
                }
            }
        }
    }
    __syncthreads();
    int psum = 0;
    #pragma unroll
    for (int q = 0; q < 32; ++q) psum += hist[tid * 32 + q];
    int incl = psum;
    for (int off = 1; off < 64; off <<= 1) {
        int t2 = __shfl_up(incl, off, 64);
        if ((tid & 63) >= off) incl += t2;
    }
    if ((tid & 63) == 63) wsum[tid >> 6] = incl;
    __syncthreads();
    int wbase = 0;
    for (int w2 = 0; w2 < (tid >> 6); ++w2) wbase += wsum[w2];
    int excl = wbase + incl - psum;
    if (excl < KSEL && KSEL <= excl + psum) {
        int run = excl;
        for (int q = 0; q < 32; ++q) {
            int h = hist[tid * 32 + q];
            if (run < KSEL && KSEL <= run + h) { s_sel = tid * 32 + q; s_krem = KSEL - run; break; }
            run += h;
        }
    }
    __syncthreads();
    const int Bsel = s_sel, krem = s_krem;

    for (int j8 = tid; j8 < N_HALF / 8; j8 += 256) {
        uint4 v = row8[j8];
        unsigned w[4] = {v.x, v.y, v.z, v.w};
        #pragma unroll
        for (int c = 0; c < 4; ++c) {
            #pragma unroll
            for (int hc = 0; hc < 2; ++hc) {
                unsigned key = hc ? (w[c] >> 16) : (w[c] & 0xFFFFu);
                int bkt = (int)(key >> 3);
                int jg = jbase + j8 * 8 + c * 2 + hc;
                if (bkt < Bsel) { int p = atomicAdd(&s_cntA, 1); lsIdx[p] = jg; }
                else if (bkt == Bsel) {
                    int p = atomicAdd(&s_cntT, 1);
                    if (p < 512) tie[p] = ((u64)key << 32) | (unsigned)jg;
                }
            }
        }
    }
    __syncthreads();
    int nt = s_cntT; if (nt > 512) nt = 512;
    for (int i = tid; i < 512; i += 256) if (i >= nt) tie[i] = ~0ull;
    __syncthreads();
    bitonic512(tie, tid);
    if (tid < krem) lsIdx[s_cntA + tid] = (int)(tie[tid] & 0xFFFFFFFFull);
    __syncthreads();
    if (tid < KSEL)
        cand[((size_t)(row0 + rloc)) * (2 * KSEL) + half * KSEL + tid] = lsIdx[tid];
}

// ---------------- K2m: exact fp32 refine of 2*KSEL candidates -> top-128 ---------
__global__ __launch_bounds__(256) void k2m(const float* __restrict__ x,
                                           const float* __restrict__ trainX,
                                           const float* __restrict__ xx,
                                           const float* __restrict__ tt,
                                           const int* __restrict__ cand,
                                           int* __restrict__ nidx,
                                           float* __restrict__ nsq) {
    __shared__ int sIdx[2 * KSEL];
    __shared__ float4 xs4[64];
    __shared__ u64 keys[512];
    const int b = blockIdx.x, tid = threadIdx.x;
    const int lane = tid & 63, wv = tid >> 6;
    for (int i = tid; i < 2 * KSEL; i += 256)
        sIdx[i] = cand[(size_t)b * (2 * KSEL) + i];
    if (tid < 64) xs4[tid] = ((const float4*)(x + (size_t)b * D_DIM))[tid];
    for (int i = tid; i < 512; i += 256) keys[i] = ~0ull;
    __syncthreads();
    const int ls = lane & 31;
    const float xxb = xx[b];
    for (int it = 0; it < (2 * KSEL) / 8; ++it) {
        int c = it * 8 + wv * 2 + (lane >> 5);
        int j = sIdx[c];
        const float4* tr = (const float4*)(trainX + (size_t)j * D_DIM);
        float4 p1 = tr[ls * 2], p2 = tr[ls * 2 + 1];
        float4 q1 = xs4[ls * 2], q2 = xs4[ls * 2 + 1];
        float d = p1.x*q1.x + p1.y*q1.y + p1.z*q1.z + p1.w*q1.w
                + p2.x*q2.x + p2.y*q2.y + p2.z*q2.z + p2.w*q2.w;
        #pragma unroll
        for (int m = 1; m < 32; m <<= 1) d += __shfl_xor(d, m, 64);
        if (ls == 0) {
            float sq = fmaxf(xxb + tt[j] - 2.0f * d, 0.f);
            keys[c] = ((u64)__float_as_uint(sq) << 32) | (unsigned)j;
        }
    }
    __syncthreads();
    bitonic512(keys, tid);
    if (tid < NN) {
        u64 e = keys[tid];
        nidx[(size_t)b * NN + tid] = (int)(e & 0xFFFFFFFFull);
        nsq[(size_t)b * NN + tid]  = __uint_as_float((unsigned)(e >> 32));
    }
}

// ---------------- K3: per-row kernel matrix + register-resident LDL^T ------------
// Elimination now runs ON THE REGISTER accumulator (acc[8][8] = each thread's 64
// entries of the 128x128 matrix). Per iter: 16 owner threads publish pivot row to
// a double-buffered LDS rowbuf (symmetry => column==row), ONE barrier, all threads
// update registers. LDS traffic/iter: 16 broadcast reads/thread vs 128 RMW before.
__global__ __launch_bounds__(256, 2) void k3_solve(
    const float* __restrict__ trainX, const float* __restrict__ trainy,
    const float* __restrict__ noise, const float* __restrict__ tt,
    const int* __restrict__ nidx, const float* __restrict__ nsq,
    const float* __restrict__ lp, const float* __restrict__ ap,
    const float* __restrict__ ymp, float* __restrict__ out) {

    __shared__ __align__(16) float Abase[128 * 129];  // GEMM staging alias + final dump
    __shared__ float rowbuf[2][NN];                   // pivot-row broadcast, dbuf
    __shared__ float yLds[NN];                        // rhs (forward-solve in place)
    __shared__ int   idxs[NN];
    __shared__ float ttn[NN], c0v[NN], wvec[NN];
    __shared__ float red[8];
    float* Xs = Abase;                                // alias during GEMM (stride 65)

    const int b = blockIdx.x;
    const int tid = threadIdx.x;
    const int tx = tid & 15, ty = tid >> 4;
    const int lane = tid & 63, wv = tid >> 6;

    const float lv = expf(lp[0]);
    const float av = expf(ap[0]);
    const float ymean = ymp[0];
    const float sc = 1.0f / (lv * 16.0f);   // sqrt(D)=16

    if (tid < NN) {
        int ix = nidx[(size_t)b * NN + tid];
        idxs[tid] = ix;
        ttn[tid] = tt[ix];
        c0v[tid] = av * expf(-sqrtf(nsq[(size_t)b * NN + tid]) * sc);
    }
    __syncthreads();

    float acc[8][8];
    #pragma unroll
    for (int u = 0; u < 8; ++u)
        #pragma unroll
        for (int v = 0; v < 8; ++v) acc[u][v] = 0.f;

    for (int c = 0; c < 4; ++c) {
        #pragma unroll
        for (int s = 0; s < 8; ++s) {
            int idx = tid + s * 256;
            int i = idx >> 4, kp = (idx & 15) << 2;
            const float* src = trainX + (size_t)idxs[i] * D_DIM + c * 64 + kp;
            float4 v4 = *(const float4*)src;
            Xs[i * 65 + kp + 0] = v4.x; Xs[i * 65 + kp + 1] = v4.y;
            Xs[i * 65 + kp + 2] = v4.z; Xs[i * 65 + kp + 3] = v4.w;
        }
        __syncthreads();
        for (int kk = 0; kk < 64; ++kk) {
            float a8[8], b8[8];
            #pragma unroll
            for (int r = 0; r < 4; ++r) {
                a8[r]     = Xs[(ty * 4 + r) * 65 + kk];
                a8[4 + r] = Xs[(64 + ty * 4 + r) * 65 + kk];
                b8[r]     = Xs[(tx * 4 + r) * 65 + kk];
                b8[4 + r] = Xs[(64 + tx * 4 + r) * 65 + kk];
            }
            #pragma unroll
            for (int u = 0; u < 8; ++u)
                #pragma unroll
                for (int v = 0; v < 8; ++v)
                    acc[u][v] = fmaf(a8[u], b8[v], acc[u][v]);
        }
        __syncthreads();
    }

    // transform acc in-place to kernel-matrix values (stays in registers)
    // ownership: i(u) = (u<4) ? ty*4+u : 64+ty*4+(u-4); j(v) likewise with tx.
    #pragma unroll
    for (int u = 0; u < 8; ++u) {
        int i = (u < 4) ? (ty * 4 + u) : (64 + ty * 4 + (u - 4));
        float ti = ttn[i];
        #pragma unroll
        for (int v = 0; v < 8; ++v) {
            int j = (v < 4) ? (tx * 4 + v) : (64 + tx * 4 + (v - 4));
            float sq = fmaxf(ti + ttn[j] - 2.0f * acc[u][v], 0.0f);
            acc[u][v] = av * expf(-sqrtf(sq) * sc);
        }
    }
    if (tid < NN) yLds[tid] = c0v[tid];               // rhs

    // ---- register LDL^T elimination with fused forward substitution ----
    for (int k = 0; k < 127; ++k) {
        const int par = k & 1;
        const int rty = (k & 63) >> 2;                // owning ty of row k
        const int uk  = (k < 64) ? (k & 3) : 4 + (k & 3);   // wave-uniform slot
        // phase 1: owners publish pivot row (all 8 column slots)
        if (ty == rty) {
            #pragma unroll
            for (int u = 0; u < 8; ++u)
                if (u == uk) {                        // uniform branch -> 8 stores
                    #pragma unroll
                    for (int v = 0; v < 8; ++v) {
                        int j = (v < 4) ? (tx * 4 + v) : (64 + tx * 4 + (v - 4));
                        rowbuf[par][j] = acc[u][v];
                    }
                }
        }
        __syncthreads();                              // phase 2 (only barrier/iter)
        // phase 3: broadcast reads + register update
        float dk = rowbuf[par][k];
        float invd = 1.0f / dk;
        float yk = yLds[k];
        float cj[8], lik[8];
        #pragma unroll
        for (int v = 0; v < 8; ++v) {
            int j = (v < 4) ? (tx * 4 + v) : (64 + tx * 4 + (v - 4));
            cj[v] = (j > k) ? rowbuf[par][j] : 0.f;
        }
        #pragma unroll
        for (int u = 0; u < 8; ++u) {
            int i = (u < 4) ? (ty * 4 + u) : (64 + ty * 4 + (u - 4));
            lik[u] = (i > k) ? rowbuf[par][i] * invd : 0.f;
        }
        #pragma unroll
        for (int u = 0; u < 8; ++u)
            #pragma unroll
            for (int v = 0; v < 8; ++v)
                acc[u][v] = fmaf(-lik[u], cj[v], acc[u][v]);
        if (tx == 0) {                                // rhs forward-solve (16 threads)
            #pragma unroll
            for (int u = 0; u < 8; ++u) {
                int i = (u < 4) ? (ty * 4 + u) : (64 + ty * 4 + (u - 4));
                if (i > k) yLds[i] = fmaf(-lik[u], yk, yLds[i]);
            }
        }
    }

    // dump factored matrix for backward substitution (one-time)
    #pragma unroll
    for (int u = 0; u < 8; ++u) {
        int i = (u < 4) ? (ty * 4 + u) : (64 + ty * 4 + (u - 4));
        #pragma unroll
        for (int v = 0; v < 8; ++v) {
            int j = (v < 4) ? (tx * 4 + v) : (64 + tx * 4 + (v - 4));
            Abase[i * 129 + j] = acc[u][v];
        }
    }
    __syncthreads();

    // backward substitution: single wave, 2 rows/lane in registers, no barriers
    if (tid < 64) {
        int l = tid;
        float y0 = yLds[l];
        float y1 = yLds[64 + l];
        for (int k = 127; k >= 0; --k) {
            float ysrc = (k >= 64) ? y1 : y0;
            float ykv = __shfl(ysrc, k & 63, 64);
            float wk = ykv / Abase[k * 129 + k];
            if (l == 0) wvec[k] = wk;
            if (l < k)      y0 = fmaf(-Abase[k * 129 + l],      wk, y0);
            if (64 + l < k) y1 = fmaf(-Abase[k * 129 + 64 + l], wk, y1);
        }
    }
    __syncthreads();

    float p1 = 0.f, p2 = 0.f;
    if (tid < NN) {
        float w = wvec[tid];
        float nyv = trainy[idxs[tid]] + 0.01f * noise[(size_t)b * NN + tid] - ymean;
        p1 = w * nyv;
        p2 = w * c0v[tid];
    }
    for (int off = 32; off; off >>= 1) {
        p1 += __shfl_down(p1, off, 64);
        p2 += __shfl_down(p2, off, 64);
    }
    if (lane == 0) { red[wv * 2] = p1; red[wv * 2 + 1] = p2; }
    __syncthreads();
    if (tid == 0) {
        out[b]        = (red[0] + red[2] + red[4] + red[6]) + ymean;
        out[B_SZ + b] = av - (red[1] + red[3] + red[5] + red[7]);
    }
}

extern "C" void kernel_launch(void* const* d_in, const int* in_sizes, int n_in,
                              void* d_out, int out_size, void* d_ws, size_t ws_size,
                              hipStream_t stream) {
    const float* x      = (const float*)d_in[0];
    const float* trainX = (const float*)d_in[1];
    const float* trainy = (const float*)d_in[2];
    const float* noise  = (const float*)d_in[3];
    const float* lp     = (const float*)d_in[4];
    const float* ap     = (const float*)d_in[5];
    const float* ymp    = (const float*)d_in[6];
    float* out = (float*)d_out;

    char* ws = (char*)d_ws;
    size_t off = 0;
    auto alloc = [&](size_t bytes) {
        void* p = ws + off;
        off = (off + bytes + 255) & ~(size_t)255;
        return p;
    };
    float* tt   = (float*)alloc((size_t)N_TRAIN * 4);
    float* xx   = (float*)alloc((size_t)B_SZ * 4);
    int*   nidb = (int*)  alloc((size_t)B_SZ * NN * 4);
    float* nsqb = (float*)alloc((size_t)B_SZ * NN * 4);
    int*   cand = (int*)  alloc((size_t)B_SZ * 2 * KSEL * 4);
    u16*   Ah   = (u16*)  alloc((size_t)B_SZ * D_DIM * 2);
    u16*   Bh   = (u16*)  alloc((size_t)N_TRAIN * D_DIM * 2);
    size_t distBytes = (ws_size > off) ? (ws_size - off) : 0;
    u16* distu = (u16*)(ws + off);
    int R = (int)(distBytes / ((size_t)N_TRAIN * 2));
    if (R > 256) R = 256;        // keep dist chunk L3-resident (51 MB)
    if (R < 1) R = 1;

    {
        int waves = N_TRAIN + B_SZ;
        k0_norms<<<(waves + 3) / 4, 256, 0, stream>>>(trainX, x, tt, xx);
    }
    kcv<<<4096, 256, 0, stream>>>(trainX, Bh, N_TRAIN * D_DIM / 4);
    kcv<<<256, 256, 0, stream>>>(x, Ah, B_SZ * D_DIM / 4);

    for (int r0 = 0; r0 < B_SZ; r0 += R) {
        int rc = (B_SZ - r0 < R) ? (B_SZ - r0) : R;
        dim3 g1((N_TRAIN + 127) / 128, (rc + 127) / 128);
        k1m<<<g1, 256, 0, stream>>>(Ah, Bh, xx, tt, distu, r0, rc);
        k2_select<<<rc * 2, 256, 0, stream>>>(distu, r0, cand);
    }
    k2m<<<B_SZ, 256, 0, stream>>>(x, trainX, xx, tt, cand, nidb, nsqb);
    k3_solve<<<B_SZ, 256, 0, stream>>>(trainX, trainy, noise, tt, nidb, nsqb,
                                       lp, ap, ymp, out);
}

// Round 7
// 1269.560 us; speedup vs baseline: 2.7570x; 1.4014x over previous
//
#include <hip/hip_runtime.h>
#include <math.h>
#include <stdint.h>

#define B_SZ    1024
#define N_TRAIN 100000
#define N_PAD   100096       // 782 tiles * 128 (permuted-position row stride)
#define D_DIM   256
#define NN      128
#define KSEL    256          // candidate count (margin 128 ranks over 128)
#define CAP     2048         // k2 collect buffer
#define SRANK   16           // k2 sample threshold rank (of 2048)

typedef unsigned short u16;
typedef unsigned long long u64;
typedef __attribute__((ext_vector_type(8))) short short8v;
typedef __attribute__((ext_vector_type(4))) float f32x4;

__device__ inline u16 f2bf(float f) {
    unsigned u = __float_as_uint(f);
    return (u16)((u + 0x7FFFu + ((u >> 16) & 1u)) >> 16);
}
__device__ inline float bf2f(u16 h) { return __uint_as_float((unsigned)h << 16); }

// ---------------- K0: squared row norms (one wave per row) ----------------
__global__ __launch_bounds__(256) void k0_norms(const float* __restrict__ trainX,
                                                const float* __restrict__ x,
                                                float* __restrict__ tt,
                                                float* __restrict__ xx) {
    int wave = (blockIdx.x * blockDim.x + threadIdx.x) >> 6;
    int lane = threadIdx.x & 63;
    if (wave >= N_TRAIN + B_SZ) return;
    const float* row = (wave < N_TRAIN) ? (trainX + (size_t)wave * D_DIM)
                                        : (x + (size_t)(wave - N_TRAIN) * D_DIM);
    float4 v = ((const float4*)row)[lane];
    float s = v.x*v.x + v.y*v.y + v.z*v.z + v.w*v.w;
    for (int off = 32; off; off >>= 1) s += __shfl_down(s, off, 64);
    if (lane == 0) { if (wave < N_TRAIN) tt[wave] = s; else xx[wave - N_TRAIN] = s; }
}

// ---------------- Kcv: fp32 -> bf16 conversion (RNE) ----------------
__global__ __launch_bounds__(256) void kcv(const float* __restrict__ src,
                                           u16* __restrict__ dst, int n4) {
    int stride = gridDim.x * 256;
    for (int i = blockIdx.x * 256 + threadIdx.x; i < n4; i += stride) {
        float4 v = ((const float4*)src)[i];
        u64 p = (u64)f2bf(v.x) | ((u64)f2bf(v.y) << 16)
              | ((u64)f2bf(v.z) << 32) | ((u64)f2bf(v.w) << 48);
        ((u64*)dst)[i] = p;
    }
}

// ---------------- K1m: bf16 MFMA GEMM -> approx sq distances (u16, permuted) ----
// Position perm within each 128-col tile: p = wc*64 + li*4 + n  <->  col = wc*64 + n*16 + li.
// OOB cols get code 0xFFFF (poison-independent). Row stride N_PAD.
__global__ __launch_bounds__(256) void k1m(const u16* __restrict__ Ah,
                                           const u16* __restrict__ Bh,
                                           const float* __restrict__ xx,
                                           const float* __restrict__ tt,
                                           u16* __restrict__ distu,
                                           int row0, int nrows) {
    __shared__ u16 Als[4][128][8];    // [kslot][row][8 bf16] -> 16B chunks
    __shared__ u16 Bls[4][128][8];
    const int tid = threadIdx.x;
    const int lane = tid & 63, wv = tid >> 6;
    const int wr = wv >> 1, wc = wv & 1;
    const int ib = blockIdx.y * 128;
    const size_t jb = (size_t)blockIdx.x * 128;

    f32x4 acc[4][4];
    #pragma unroll
    for (int m = 0; m < 4; ++m)
        #pragma unroll
        for (int n = 0; n < 4; ++n)
            #pragma unroll
            for (int r = 0; r < 4; ++r) acc[m][n][r] = 0.f;

    for (int k0 = 0; k0 < D_DIM; k0 += 32) {
        #pragma unroll
        for (int r = 0; r < 2; ++r) {
            int c = tid + r * 256;            // 0..511
            int row = c >> 2, ks = c & 3;
            uint4 va = make_uint4(0, 0, 0, 0);
            if (ib + row < nrows)
                va = *(const uint4*)(Ah + (size_t)(row0 + ib + row) * D_DIM + k0 + ks * 8);
            *(uint4*)(&Als[ks][row][0]) = va;
            uint4 vb = make_uint4(0, 0, 0, 0);
            if (jb + row < N_TRAIN)
                vb = *(const uint4*)(Bh + (jb + row) * D_DIM + k0 + ks * 8);
            *(uint4*)(&Bls[ks][row][0]) = vb;
        }
        __syncthreads();
        const int ksl = lane >> 4, li = lane & 15;
        short8v a[4], b[4];
        #pragma unroll
        for (int m = 0; m < 4; ++m)
            a[m] = *(const short8v*)&Als[ksl][wr * 64 + m * 16 + li][0];
        #pragma unroll
        for (int n = 0; n < 4; ++n)
            b[n] = *(const short8v*)&Bls[ksl][wc * 64 + n * 16 + li][0];
        #pragma unroll
        for (int m = 0; m < 4; ++m)
            #pragma unroll
            for (int n = 0; n < 4; ++n)
                acc[m][n] = __builtin_amdgcn_mfma_f32_16x16x32_bf16(a[m], b[n], acc[m][n], 0, 0, 0);
        __syncthreads();
    }
    // epilogue: C row = (lane>>4)*4 + reg, col = lane&15; packed u64 permuted store
    const int li = lane & 15, lh = lane >> 4;
    float ttv[4]; int cols[4];
    #pragma unroll
    for (int n = 0; n < 4; ++n) {
        cols[n] = (int)jb + wc * 64 + n * 16 + li;
        ttv[n] = (cols[n] < N_TRAIN) ? tt[cols[n]] : 0.f;
    }
    #pragma unroll
    for (int m = 0; m < 4; ++m)
        #pragma unroll
        for (int r = 0; r < 4; ++r) {
            int rl = ib + wr * 64 + m * 16 + lh * 4 + r;
            if (rl >= nrows) continue;
            float xi = xx[row0 + rl];
            u64 pk = 0;
            #pragma unroll
            for (int n = 0; n < 4; ++n) {
                u16 code = 0xFFFFu;
                if (cols[n] < N_TRAIN)
                    code = f2bf(fmaxf(xi + ttv[n] - 2.0f * acc[m][n][r], 0.f));
                pk |= (u64)code << (16 * n);
            }
            *(u64*)(distu + (size_t)rl * N_PAD + jb + wc * 64 + li * 4) = pk;
        }
}

// ---------------- sort helpers (256 threads) ----------------
__device__ inline void bitonicU64N(u64* a, int tid, int NE) {
    for (int ks = 2; ks <= NE; ks <<= 1)
        for (int js = ks >> 1; js > 0; js >>= 1) {
            __syncthreads();
            for (int e = tid; e < NE; e += 256) {
                int p = e ^ js;
                if (p > e) {
                    u64 A = a[e], B = a[p];
                    if ((A > B) == ((e & ks) == 0)) { a[e] = B; a[p] = A; }
                }
            }
        }
    __syncthreads();
}
__device__ inline void bitonicU16N(u16* a, int tid, int NE) {
    for (int ks = 2; ks <= NE; ks <<= 1)
        for (int js = ks >> 1; js > 0; js >>= 1) {
            __syncthreads();
            for (int e = tid; e < NE; e += 256) {
                int p = e ^ js;
                if (p > e) {
                    u16 A = a[e], B = a[p];
                    if ((A > B) == ((e & ks) == 0)) { a[e] = B; a[p] = A; }
                }
            }
        }
    __syncthreads();
}

// ---------------- K2: per-row approx top-KSEL via sample-threshold collect ------
// Sort 2048 sampled codes -> threshold T = sample[SRANK] (expected full count ~780).
// One scan collects code<T (deterministic widen/narrow loop guarantees
// KSEL <= count <= CAP); sort collected; emit top KSEL (decoded to true col idx).
__global__ __launch_bounds__(256) void k2_select(const u16* __restrict__ distu, int row0,
                                                 int* __restrict__ cand) {
    const int tid = threadIdx.x;
    const u16* row = distu + (size_t)blockIdx.x * N_PAD;
    const uint4* row8 = (const uint4*)row;
    __shared__ u64 buf[CAP];            // 16 KB; overlaid by u16 sample array
    __shared__ int s_cnt;
    u16* samp = (u16*)buf;

    // sample positions 0..2047
    ((uint4*)samp)[tid] = row8[tid];
    __syncthreads();
    bitonicU16N(samp, tid, 2048);
    int Tc = (int)samp[SRANK];
    __syncthreads();                    // samp dead; buf reuse

    int cnt = 0;
    for (int att = 0; att < 8; ++att) {
        if (tid == 0) s_cnt = 0;
        __syncthreads();
        for (int j8 = tid; j8 < N_PAD / 8; j8 += 256) {
            uint4 v = row8[j8];
            unsigned w_[4] = {v.x, v.y, v.z, v.w};
            #pragma unroll
            for (int c2 = 0; c2 < 4; ++c2) {
                #pragma unroll
                for (int hc = 0; hc < 2; ++hc) {
                    int code = (int)(hc ? (w_[c2] >> 16) : (w_[c2] & 0xFFFFu));
                    if (code < Tc) {
                        int p = atomicAdd(&s_cnt, 1);
                        if (p < CAP) buf[p] = ((u64)(unsigned)code << 32)
                                            | (unsigned)(j8 * 8 + c2 * 2 + hc);
                    }
                }
            }
        }
        __syncthreads();
        cnt = s_cnt;
        if (cnt >= KSEL && cnt <= CAP) break;
        Tc += (cnt < KSEL) ? 8 : -8;
        __syncthreads();
    }
    if (cnt > CAP) cnt = CAP;
    for (int i = tid; i < CAP; i += 256) if (i >= cnt) buf[i] = ~0ull;
    __syncthreads();
    bitonicU64N(buf, tid, CAP);
    {   // each thread outputs one candidate (KSEL == 256 == blockDim)
        u64 e = buf[tid];
        int jraw = (e == ~0ull) ? 0 : (int)(e & 0xFFFFFFFFull);
        int base = (jraw >> 7) << 7, off = jraw & 127;
        int col = base + (off & 64) + ((off & 3) << 4) + ((off & 63) >> 2);
        cand[(size_t)(row0 + blockIdx.x) * KSEL + tid] = col;
    }
}

// ---------------- K2m: exact fp32 refine of KSEL candidates -> top-128 -----------
__global__ __launch_bounds__(256) void k2m(const float* __restrict__ x,
                                           const float* __restrict__ trainX,
                                           const float* __restrict__ xx,
                                           const float* __restrict__ tt,
                                           const int* __restrict__ cand,
                                           int* __restrict__ nidx,
                                           float* __restrict__ nsq) {
    __shared__ int sIdx[KSEL];
    __shared__ float4 xs4[64];
    __shared__ u64 keys[KSEL];
    const int b = blockIdx.x, tid = threadIdx.x;
    const int lane = tid & 63, wv = tid >> 6;
    sIdx[tid] = cand[(size_t)b * KSEL + tid];
    if (tid < 64) xs4[tid] = ((const float4*)(x + (size_t)b * D_DIM))[tid];
    __syncthreads();
    const int ls = lane & 31;
    const float xxb = xx[b];
    for (int it = 0; it < KSEL / 8; ++it) {
        int c = it * 8 + wv * 2 + (lane >> 5);
        int j = sIdx[c];
        const float4* tr = (const float4*)(trainX + (size_t)j * D_DIM);
        float4 p1 = tr[ls * 2], p2 = tr[ls * 2 + 1];
        float4 q1 = xs4[ls * 2], q2 = xs4[ls * 2 + 1];
        float d = p1.x*q1.x + p1.y*q1.y + p1.z*q1.z + p1.w*q1.w
                + p2.x*q2.x + p2.y*q2.y + p2.z*q2.z + p2.w*q2.w;
        #pragma unroll
        for (int m = 1; m < 32; m <<= 1) d += __shfl_xor(d, m, 64);
        if (ls == 0) {
            float sq = fmaxf(xxb + tt[j] - 2.0f * d, 0.f);
            keys[c] = ((u64)__float_as_uint(sq) << 32) | (unsigned)j;
        }
    }
    __syncthreads();
    bitonicU64N(keys, tid, KSEL);
    if (tid < NN) {
        u64 e = keys[tid];
        nidx[(size_t)b * NN + tid] = (int)(e & 0xFFFFFFFFull);
        nsq[(size_t)b * NN + tid]  = __uint_as_float((unsigned)(e >> 32));
    }
}

// ---------------- K3: split-bf16 MFMA Gram + register LDL^T + outputs ------------
// Gram via 3 MFMA passes (hi*hi + hi*lo + lo*hi), sq err ~1e-3. Elimination and
// backward substitution run on the MFMA C-layout register tiles; only the 128-entry
// pivot row transits LDS per iteration. No 66KB matrix in LDS -> 4 blocks/CU.
__global__ __launch_bounds__(256, 4) void k3_solve(
    const float* __restrict__ trainX, const float* __restrict__ trainy,
    const float* __restrict__ noise, const float* __restrict__ tt,
    const int* __restrict__ nidx, const float* __restrict__ nsq,
    const float* __restrict__ lp, const float* __restrict__ ap,
    const float* __restrict__ ymp, float* __restrict__ out) {

    __shared__ u16 Shi[128][40];        // 40-short row stride: 16B aligned, bank-spread
    __shared__ u16 Slo[128][40];
    __shared__ float rowbuf[2][NN];
    __shared__ float yLds[NN], dvec[NN], wvec[NN];
    __shared__ int   idxs[NN];
    __shared__ float ttn[NN], c0v[NN];
    __shared__ float red[8];

    const int b = blockIdx.x;
    const int tid = threadIdx.x;
    const int lane = tid & 63, wv = tid >> 6;
    const int wr = wv >> 1, wc = wv & 1;
    const int lr = lane & 15, lq = lane >> 4;   // C-layout: col-lane, row-quad

    const float lv = expf(lp[0]);
    const float av = expf(ap[0]);
    const float ymean = ymp[0];
    const float sc = 1.0f / (lv * 16.0f);   // sqrt(D)=16

    if (tid < NN) {
        int ix = nidx[(size_t)b * NN + tid];
        idxs[tid] = ix;
        ttn[tid] = tt[ix];
        float cc = av * expf(-sqrtf(nsq[(size_t)b * NN + tid]) * sc);
        c0v[tid] = cc;
        yLds[tid] = cc;                 // rhs
    }
    __syncthreads();

    f32x4 acc[4][4];
    #pragma unroll
    for (int m = 0; m < 4; ++m)
        #pragma unroll
        for (int n = 0; n < 4; ++n)
            #pragma unroll
            for (int r = 0; r < 4; ++r) acc[m][n][r] = 0.f;

    for (int c = 0; c < 8; ++c) {       // 8 chunks of 32 dims
        #pragma unroll
        for (int s = 0; s < 4; ++s) {
            int idx = tid + s * 256;    // 0..1023 = 128 rows x 8 float4
            int row = idx >> 3, kp = (idx & 7) << 2;
            float4 v = *(const float4*)(trainX + (size_t)idxs[row] * D_DIM + c * 32 + kp);
            u16 h0 = f2bf(v.x), h1 = f2bf(v.y), h2 = f2bf(v.z), h3 = f2bf(v.w);
            u16 l0 = f2bf(v.x - bf2f(h0)), l1 = f2bf(v.y - bf2f(h1));
            u16 l2 = f2bf(v.z - bf2f(h2)), l3 = f2bf(v.w - bf2f(h3));
            *(u64*)&Shi[row][kp] = (u64)h0 | ((u64)h1 << 16) | ((u64)h2 << 32) | ((u64)h3 << 48);
            *(u64*)&Slo[row][kp] = (u64)l0 | ((u64)l1 << 16) | ((u64)l2 << 32) | ((u64)l3 << 48);
        }
        __syncthreads();
        {
            short8v ahi[4], bhi[4], bb[4];
            #pragma unroll
            for (int m = 0; m < 4; ++m)
                ahi[m] = *(const short8v*)&Shi[wr * 64 + m * 16 + lr][lq * 8];
            #pragma unroll
            for (int n = 0; n < 4; ++n)
                bhi[n] = *(const short8v*)&Shi[wc * 64 + n * 16 + lr][lq * 8];
            #pragma unroll
            for (int m = 0; m < 4; ++m)
                #pragma unroll
                for (int n = 0; n < 4; ++n)
                    acc[m][n] = __builtin_amdgcn_mfma_f32_16x16x32_bf16(ahi[m], bhi[n], acc[m][n], 0, 0, 0);
            #pragma unroll
            for (int n = 0; n < 4; ++n)             // b-lo pass
                bb[n] = *(const short8v*)&Slo[wc * 64 + n * 16 + lr][lq * 8];
            #pragma unroll
            for (int m = 0; m < 4; ++m)
                #pragma unroll
                for (int n = 0; n < 4; ++n)
                    acc[m][n] = __builtin_amdgcn_mfma_f32_16x16x32_bf16(ahi[m], bb[n], acc[m][n], 0, 0, 0);
            #pragma unroll
            for (int m = 0; m < 4; ++m)             // a-lo pass (reuse bb regs)
                bb[m] = *(const short8v*)&Slo[wr * 64 + m * 16 + lr][lq * 8];
            #pragma unroll
            for (int m = 0; m < 4; ++m)
                #pragma unroll
                for (int n = 0; n < 4; ++n)
                    acc[m][n] = __builtin_amdgcn_mfma_f32_16x16x32_bf16(bb[m], bhi[n], acc[m][n], 0, 0, 0);
        }
        __syncthreads();
    }

    // transform acc -> kernel matrix values (in registers)
    #pragma unroll
    for (int m = 0; m < 4; ++m) {
        #pragma unroll
        for (int r = 0; r < 4; ++r) {
            int i = wr * 64 + m * 16 + lq * 4 + r;
            float ti = ttn[i];
            #pragma unroll
            for (int n = 0; n < 4; ++n) {
                int j = wc * 64 + n * 16 + lr;
                float sq = fmaxf(ti + ttn[j] - 2.0f * acc[m][n][r], 0.0f);
                acc[m][n][r] = av * expf(-sqrtf(sq) * sc);
            }
        }
    }

    // ---- forward LDL^T elimination on register tiles (1 barrier/iter) ----
    for (int k = 0; k < 127; ++k) {
        const int par = k & 1;
        if (wr == (k >> 6) && lq == ((k & 15) >> 2)) {     // pivot-row owners
            #pragma unroll
            for (int mm = 0; mm < 4; ++mm)
                if (mm == ((k >> 4) & 3)) {
                    #pragma unroll
                    for (int rr = 0; rr < 4; ++rr)
                        if (rr == (k & 3)) {
                            #pragma unroll
                            for (int n = 0; n < 4; ++n)
                                rowbuf[par][wc * 64 + n * 16 + lr] = acc[mm][n][rr];
                        }
                }
        }
        __syncthreads();
        float invd = 1.0f / rowbuf[par][k];
        float yk = yLds[k];
        float cj[4], lik[4][4];
        #pragma unroll
        for (int n = 0; n < 4; ++n) {
            int j = wc * 64 + n * 16 + lr;
            cj[n] = (j > k) ? rowbuf[par][j] : 0.f;
        }
        #pragma unroll
        for (int m = 0; m < 4; ++m)
            #pragma unroll
            for (int r = 0; r < 4; ++r) {
                int i = wr * 64 + m * 16 + lq * 4 + r;
                lik[m][r] = (i > k) ? rowbuf[par][i] * invd : 0.f;
            }
        #pragma unroll
        for (int m = 0; m < 4; ++m)
            #pragma unroll
            for (int n = 0; n < 4; ++n)
                #pragma unroll
                for (int r = 0; r < 4; ++r)
                    acc[m][n][r] = fmaf(-lik[m][r], cj[n], acc[m][n][r]);
        if (wc == 0 && lr == 0) {       // rhs forward-solve (8 owner lanes)
            #pragma unroll
            for (int m = 0; m < 4; ++m)
                #pragma unroll
                for (int r = 0; r < 4; ++r) {
                    int i = wr * 64 + m * 16 + lq * 4 + r;
                    if (i > k) yLds[i] = fmaf(-lik[m][r], yk, yLds[i]);
                }
        }
        if (tid == 0) dvec[k] = rowbuf[par][k];
    }
    if (wv == 3 && lane == 63) dvec[127] = acc[3][3][3];   // last diag
    __syncthreads();

    // ---- backward substitution, distributed (column-k owners update) ----
    for (int k = 127; k >= 0; --k) {
        float wk = yLds[k] / dvec[k];
        if (tid == 0) wvec[k] = wk;
        if (wc == (k >> 6) && lr == (k & 15)) {
            #pragma unroll
            for (int nn = 0; nn < 4; ++nn)
                if (nn == ((k >> 4) & 3)) {
                    #pragma unroll
                    for (int m = 0; m < 4; ++m)
                        #pragma unroll
                        for (int r = 0; r < 4; ++r) {
                            int i = wr * 64 + m * 16 + lq * 4 + r;
                            if (i < k) yLds[i] = fmaf(-acc[m][nn][r], wk, yLds[i]);
                        }
                }
        }
        __syncthreads();
    }

    float p1 = 0.f, p2 = 0.f;
    if (tid < NN) {
        float w = wvec[tid];
        float nyv = trainy[idxs[tid]] + 0.01f * noise[(size_t)b * NN + tid] - ymean;
        p1 = w * nyv;
        p2 = w * c0v[tid];
    }
    for (int off = 32; off; off >>= 1) {
        p1 += __shfl_down(p1, off, 64);
        p2 += __shfl_down(p2, off, 64);
    }
    if ((tid & 63) == 0) { red[wv * 2] = p1; red[wv * 2 + 1] = p2; }
    __syncthreads();
    if (tid == 0) {
        out[b]        = (red[0] + red[2] + red[4] + red[6]) + ymean;
        out[B_SZ + b] = av - (red[1] + red[3] + red[5] + red[7]);
    }
}

extern "C" void kernel_launch(void* const* d_in, const int* in_sizes, int n_in,
                              void* d_out, int out_size, void* d_ws, size_t ws_size,
                              hipStream_t stream) {
    const float* x      = (const float*)d_in[0];
    const float* trainX = (const float*)d_in[1];
    const float* trainy = (const float*)d_in[2];
    const float* noise  = (const float*)d_in[3];
    const float* lp     = (const float*)d_in[4];
    const float* ap     = (const float*)d_in[5];
    const float* ymp    = (const float*)d_in[6];
    float* out = (float*)d_out;

    char* ws = (char*)d_ws;
    size_t off = 0;
    auto alloc = [&](size_t bytes) {
        void* p = ws + off;
        off = (off + bytes + 255) & ~(size_t)255;
        return p;
    };
    float* tt   = (float*)alloc((size_t)N_TRAIN * 4);
    float* xx   = (float*)alloc((size_t)B_SZ * 4);
    int*   nidb = (int*)  alloc((size_t)B_SZ * NN * 4);
    float* nsqb = (float*)alloc((size_t)B_SZ * NN * 4);
    int*   cand = (int*)  alloc((size_t)B_SZ * KSEL * 4);
    u16*   Ah   = (u16*)  alloc((size_t)B_SZ * D_DIM * 2);
    u16*   Bh   = (u16*)  alloc((size_t)N_TRAIN * D_DIM * 2);
    size_t distBytes = (ws_size > off) ? (ws_size - off) : 0;
    u16* distu = (u16*)(ws + off);
    int R = (int)(distBytes / ((size_t)N_PAD * 2));
    if (R > 256) R = 256;        // keep dist chunk L3-resident (51 MB)
    if (R < 1) R = 1;

    {
        int waves = N_TRAIN + B_SZ;
        k0_norms<<<(waves + 3) / 4, 256, 0, stream>>>(trainX, x, tt, xx);
    }
    kcv<<<4096, 256, 0, stream>>>(trainX, Bh, N_TRAIN * D_DIM / 4);
    kcv<<<256, 256, 0, stream>>>(x, Ah, B_SZ * D_DIM / 4);

    for (int r0 = 0; r0 < B_SZ; r0 += R) {
        int rc = (B_SZ - r0 < R) ? (B_SZ - r0) : R;
        dim3 g1((N_TRAIN + 127) / 128, (rc + 127) / 128);
        k1m<<<g1, 256, 0, stream>>>(Ah, Bh, xx, tt, distu, r0, rc);
        k2_select<<<rc, 256, 0, stream>>>(distu, r0, cand);
    }
    k2m<<<B_SZ, 256, 0, stream>>>(x, trainX, xx, tt, cand, nidb, nsqb);
    k3_solve<<<B_SZ, 256, 0, stream>>>(trainX, trainy, noise, tt, nidb, nsqb,
                                       lp, ap, ymp, out);
}

// Round 8
// 1152.792 us; speedup vs baseline: 3.0362x; 1.1013x over previous
//
#include <hip/hip_runtime.h>
#include <math.h>
#include <stdint.h>

#define B_SZ    1024
#define N_TRAIN 100000
#define N_PAD   100096       // 782 tiles * 128 (permuted-position row stride)
#define D_DIM   256
#define NN      128
#define KSEL    256          // candidate count (margin 128 ranks over 128)
#define CAP     2048         // k2 collect buffer
#define SRANK   16           // k2 sample threshold rank (of 2048)

typedef unsigned short u16;
typedef unsigned long long u64;
typedef __attribute__((ext_vector_type(8))) short short8v;
typedef __attribute__((ext_vector_type(4))) float f32x4;

__device__ inline u16 f2bf(float f) {
    unsigned u = __float_as_uint(f);
    return (u16)((u + 0x7FFFu + ((u >> 16) & 1u)) >> 16);
}
__device__ inline float bf2f(u16 h) { return __uint_as_float((unsigned)h << 16); }

// ---------------- K0: squared row norms (one wave per row) ----------------
__global__ __launch_bounds__(256) void k0_norms(const float* __restrict__ trainX,
                                                const float* __restrict__ x,
                                                float* __restrict__ tt,
                                                float* __restrict__ xx) {
    int wave = (blockIdx.x * blockDim.x + threadIdx.x) >> 6;
    int lane = threadIdx.x & 63;
    if (wave >= N_TRAIN + B_SZ) return;
    const float* row = (wave < N_TRAIN) ? (trainX + (size_t)wave * D_DIM)
                                        : (x + (size_t)(wave - N_TRAIN) * D_DIM);
    float4 v = ((const float4*)row)[lane];
    float s = v.x*v.x + v.y*v.y + v.z*v.z + v.w*v.w;
    for (int off = 32; off; off >>= 1) s += __shfl_down(s, off, 64);
    if (lane == 0) { if (wave < N_TRAIN) tt[wave] = s; else xx[wave - N_TRAIN] = s; }
}

// ---------------- Kcv: fp32 -> bf16 hi (RNE) ----------------
__global__ __launch_bounds__(256) void kcv(const float* __restrict__ src,
                                           u16* __restrict__ dst, int n4) {
    int stride = gridDim.x * 256;
    for (int i = blockIdx.x * 256 + threadIdx.x; i < n4; i += stride) {
        float4 v = ((const float4*)src)[i];
        u64 p = (u64)f2bf(v.x) | ((u64)f2bf(v.y) << 16)
              | ((u64)f2bf(v.z) << 32) | ((u64)f2bf(v.w) << 48);
        ((u64*)dst)[i] = p;
    }
}

// ---------------- Kcv2: fp32 -> split bf16 hi + lo ----------------
__global__ __launch_bounds__(256) void kcv2(const float* __restrict__ src,
                                            u16* __restrict__ dstH,
                                            u16* __restrict__ dstL, int n4) {
    int stride = gridDim.x * 256;
    for (int i = blockIdx.x * 256 + threadIdx.x; i < n4; i += stride) {
        float4 v = ((const float4*)src)[i];
        u16 h0 = f2bf(v.x), h1 = f2bf(v.y), h2 = f2bf(v.z), h3 = f2bf(v.w);
        u16 l0 = f2bf(v.x - bf2f(h0)), l1 = f2bf(v.y - bf2f(h1));
        u16 l2 = f2bf(v.z - bf2f(h2)), l3 = f2bf(v.w - bf2f(h3));
        ((u64*)dstH)[i] = (u64)h0 | ((u64)h1 << 16) | ((u64)h2 << 32) | ((u64)h3 << 48);
        ((u64*)dstL)[i] = (u64)l0 | ((u64)l1 << 16) | ((u64)l2 << 32) | ((u64)l3 << 48);
    }
}

// ---------------- K1m: bf16 MFMA GEMM -> approx sq distances (u16, permuted) ----
__global__ __launch_bounds__(256) void k1m(const u16* __restrict__ Ah,
                                           const u16* __restrict__ Bh,
                                           const float* __restrict__ xx,
                                           const float* __restrict__ tt,
                                           u16* __restrict__ distu,
                                           int row0, int nrows) {
    __shared__ u16 Als[4][128][8];    // [kslot][row][8 bf16] -> 16B chunks
    __shared__ u16 Bls[4][128][8];
    const int tid = threadIdx.x;
    const int lane = tid & 63, wv = tid >> 6;
    const int wr = wv >> 1, wc = wv & 1;
    const int ib = blockIdx.y * 128;
    const size_t jb = (size_t)blockIdx.x * 128;

    f32x4 acc[4][4];
    #pragma unroll
    for (int m = 0; m < 4; ++m)
        #pragma unroll
        for (int n = 0; n < 4; ++n)
            #pragma unroll
            for (int r = 0; r < 4; ++r) acc[m][n][r] = 0.f;

    for (int k0 = 0; k0 < D_DIM; k0 += 32) {
        #pragma unroll
        for (int r = 0; r < 2; ++r) {
            int c = tid + r * 256;            // 0..511
            int row = c >> 2, ks = c & 3;
            uint4 va = make_uint4(0, 0, 0, 0);
            if (ib + row < nrows)
                va = *(const uint4*)(Ah + (size_t)(row0 + ib + row) * D_DIM + k0 + ks * 8);
            *(uint4*)(&Als[ks][row][0]) = va;
            uint4 vb = make_uint4(0, 0, 0, 0);
            if (jb + row < N_TRAIN)
                vb = *(const uint4*)(Bh + (jb + row) * D_DIM + k0 + ks * 8);
            *(uint4*)(&Bls[ks][row][0]) = vb;
        }
        __syncthreads();
        const int ksl = lane >> 4, li = lane & 15;
        short8v a[4], b[4];
        #pragma unroll
        for (int m = 0; m < 4; ++m)
            a[m] = *(const short8v*)&Als[ksl][wr * 64 + m * 16 + li][0];
        #pragma unroll
        for (int n = 0; n < 4; ++n)
            b[n] = *(const short8v*)&Bls[ksl][wc * 64 + n * 16 + li][0];
        #pragma unroll
        for (int m = 0; m < 4; ++m)
            #pragma unroll
            for (int n = 0; n < 4; ++n)
                acc[m][n] = __builtin_amdgcn_mfma_f32_16x16x32_bf16(a[m], b[n], acc[m][n], 0, 0, 0);
        __syncthreads();
    }
    // epilogue: C row = (lane>>4)*4 + reg, col = lane&15; packed u64 permuted store
    const int li = lane & 15, lh = lane >> 4;
    float ttv[4]; int cols[4];
    #pragma unroll
    for (int n = 0; n < 4; ++n) {
        cols[n] = (int)jb + wc * 64 + n * 16 + li;
        ttv[n] = (cols[n] < N_TRAIN) ? tt[cols[n]] : 0.f;
    }
    #pragma unroll
    for (int m = 0; m < 4; ++m)
        #pragma unroll
        for (int r = 0; r < 4; ++r) {
            int rl = ib + wr * 64 + m * 16 + lh * 4 + r;
            if (rl >= nrows) continue;
            float xi = xx[row0 + rl];
            u64 pk = 0;
            #pragma unroll
            for (int n = 0; n < 4; ++n) {
                u16 code = 0xFFFFu;
                if (cols[n] < N_TRAIN)
                    code = f2bf(fmaxf(xi + ttv[n] - 2.0f * acc[m][n][r], 0.f));
                pk |= (u64)code << (16 * n);
            }
            *(u64*)(distu + (size_t)rl * N_PAD + jb + wc * 64 + li * 4) = pk;
        }
}

// ---------------- sort helpers (256 threads) ----------------
__device__ inline void bitonicU64N(u64* a, int tid, int NE) {
    for (int ks = 2; ks <= NE; ks <<= 1)
        for (int js = ks >> 1; js > 0; js >>= 1) {
            __syncthreads();
            for (int e = tid; e < NE; e += 256) {
                int p = e ^ js;
                if (p > e) {
                    u64 A = a[e], B = a[p];
                    if ((A > B) == ((e & ks) == 0)) { a[e] = B; a[p] = A; }
                }
            }
        }
    __syncthreads();
}
__device__ inline void bitonicU16N(u16* a, int tid, int NE) {
    for (int ks = 2; ks <= NE; ks <<= 1)
        for (int js = ks >> 1; js > 0; js >>= 1) {
            __syncthreads();
            for (int e = tid; e < NE; e += 256) {
                int p = e ^ js;
                if (p > e) {
                    u16 A = a[e], B = a[p];
                    if ((A > B) == ((e & ks) == 0)) { a[e] = B; a[p] = A; }
                }
            }
        }
    __syncthreads();
}

// ---------------- K2: per-row approx top-KSEL via sample-threshold collect ------
__global__ __launch_bounds__(256) void k2_select(const u16* __restrict__ distu, int row0,
                                                 int* __restrict__ cand) {
    const int tid = threadIdx.x;
    const u16* row = distu + (size_t)blockIdx.x * N_PAD;
    const uint4* row8 = (const uint4*)row;
    __shared__ u64 buf[CAP];            // 16 KB; overlaid by u16 sample array
    __shared__ int s_cnt;
    u16* samp = (u16*)buf;

    // sample positions 0..2047
    ((uint4*)samp)[tid] = row8[tid];
    __syncthreads();
    bitonicU16N(samp, tid, 2048);
    int Tc = (int)samp[SRANK];
    __syncthreads();                    // samp dead; buf reuse

    int cnt = 0;
    for (int att = 0; att < 8; ++att) {
        if (tid == 0) s_cnt = 0;
        __syncthreads();
        for (int j8 = tid; j8 < N_PAD / 8; j8 += 256) {
            uint4 v = row8[j8];
            unsigned w_[4] = {v.x, v.y, v.z, v.w};
            #pragma unroll
            for (int c2 = 0; c2 < 4; ++c2) {
                #pragma unroll
                for (int hc = 0; hc < 2; ++hc) {
                    int code = (int)(hc ? (w_[c2] >> 16) : (w_[c2] & 0xFFFFu));
                    if (code < Tc) {
                        int p = atomicAdd(&s_cnt, 1);
                        if (p < CAP) buf[p] = ((u64)(unsigned)code << 32)
                                            | (unsigned)(j8 * 8 + c2 * 2 + hc);
                    }
                }
            }
        }
        __syncthreads();
        cnt = s_cnt;
        if (cnt >= KSEL && cnt <= CAP) break;
        Tc += (cnt < KSEL) ? 8 : -8;
        __syncthreads();
    }
    if (cnt > CAP) cnt = CAP;
    for (int i = tid; i < CAP; i += 256) if (i >= cnt) buf[i] = ~0ull;
    __syncthreads();
    bitonicU64N(buf, tid, CAP);
    {   // each thread outputs one candidate (KSEL == 256 == blockDim)
        u64 e = buf[tid];
        int jraw = (e == ~0ull) ? 0 : (int)(e & 0xFFFFFFFFull);
        int base = (jraw >> 7) << 7, off = jraw & 127;
        int col = base + (off & 64) + ((off & 3) << 4) + ((off & 63) >> 2);
        cand[(size_t)(row0 + blockIdx.x) * KSEL + tid] = col;
    }
}

// ---------------- K2m: exact fp32 refine of KSEL candidates -> top-128 -----------
__global__ __launch_bounds__(256) void k2m(const float* __restrict__ x,
                                           const float* __restrict__ trainX,
                                           const float* __restrict__ xx,
                                           const float* __restrict__ tt,
                                           const int* __restrict__ cand,
                                           int* __restrict__ nidx,
                                           float* __restrict__ nsq) {
    __shared__ int sIdx[KSEL];
    __shared__ float4 xs4[64];
    __shared__ u64 keys[KSEL];
    const int b = blockIdx.x, tid = threadIdx.x;
    const int lane = tid & 63, wv = tid >> 6;
    sIdx[tid] = cand[(size_t)b * KSEL + tid];
    if (tid < 64) xs4[tid] = ((const float4*)(x + (size_t)b * D_DIM))[tid];
    __syncthreads();
    const int ls = lane & 31;
    const float xxb = xx[b];
    for (int it = 0; it < KSEL / 8; ++it) {
        int c = it * 8 + wv * 2 + (lane >> 5);
        int j = sIdx[c];
        const float4* tr = (const float4*)(trainX + (size_t)j * D_DIM);
        float4 p1 = tr[ls * 2], p2 = tr[ls * 2 + 1];
        float4 q1 = xs4[ls * 2], q2 = xs4[ls * 2 + 1];
        float d = p1.x*q1.x + p1.y*q1.y + p1.z*q1.z + p1.w*q1.w
                + p2.x*q2.x + p2.y*q2.y + p2.z*q2.z + p2.w*q2.w;
        #pragma unroll
        for (int m = 1; m < 32; m <<= 1) d += __shfl_xor(d, m, 64);
        if (ls == 0) {
            float sq = fmaxf(xxb + tt[j] - 2.0f * d, 0.f);
            keys[c] = ((u64)__float_as_uint(sq) << 32) | (unsigned)j;
        }
    }
    __syncthreads();
    bitonicU64N(keys, tid, KSEL);
    if (tid < NN) {
        u64 e = keys[tid];
        nidx[(size_t)b * NN + tid] = (int)(e & 0xFFFFFFFFull);
        nsq[(size_t)b * NN + tid]  = __uint_as_float((unsigned)(e >> 32));
    }
}

// ---------------- K3: MFMA Gram (pre-split bf16) + rank-4 blocked LDL^T ----------
// Forward: 32 blocks of 4 pivots; publish 4 raw rows, 1 barrier, uniform 4x4 Crout,
// rank-4 register update. Backward: publish 4 factored cols, uniform 4x4 solve,
// rank-4 y update. Barriers ~85 vs 263 (R7). Staging gathers pre-split Bh/Bl bf16.
__global__ __launch_bounds__(256, 4) void k3_solve(
    const u16* __restrict__ Bh, const u16* __restrict__ Bl,
    const float* __restrict__ trainy,
    const float* __restrict__ noise, const float* __restrict__ tt,
    const int* __restrict__ nidx, const float* __restrict__ nsq,
    const float* __restrict__ lp, const float* __restrict__ ap,
    const float* __restrict__ ymp, float* __restrict__ out) {

    __shared__ u16 Shi[128][40];
    __shared__ u16 Slo[128][40];
    __shared__ float pbuf[2][4][NN];    // pivot rows (fwd) / cols (bwd), dbuf
    __shared__ float yLds[NN], yfwd[NN], dvec[NN], wvec[NN];
    __shared__ int   idxs[NN];
    __shared__ float ttn[NN], c0v[NN];
    __shared__ float red[8];

    const int b = blockIdx.x;
    const int tid = threadIdx.x;
    const int lane = tid & 63, wv = tid >> 6;
    const int wr = wv >> 1, wc = wv & 1;
    const int lr = lane & 15, lq = lane >> 4;   // C-layout: col-lane, row-quad

    const float lv = expf(lp[0]);
    const float av = expf(ap[0]);
    const float ymean = ymp[0];
    const float sc = 1.0f / (lv * 16.0f);   // sqrt(D)=16

    if (tid < NN) {
        int ix = nidx[(size_t)b * NN + tid];
        idxs[tid] = ix;
        ttn[tid] = tt[ix];
        float cc = av * expf(-sqrtf(nsq[(size_t)b * NN + tid]) * sc);
        c0v[tid] = cc;
        yLds[tid] = cc;                 // rhs
    }
    __syncthreads();

    f32x4 acc[4][4];
    #pragma unroll
    for (int m = 0; m < 4; ++m)
        #pragma unroll
        for (int n = 0; n < 4; ++n)
            #pragma unroll
            for (int r = 0; r < 4; ++r) acc[m][n][r] = 0.f;

    for (int c = 0; c < 8; ++c) {       // 8 chunks of 32 dims, gathered pre-split
        #pragma unroll
        for (int s = 0; s < 2; ++s) {
            int idx = tid + s * 256;    // 0..511 = 128 rows x 4 uint4
            int row = idx >> 2, kp = (idx & 3) << 3;
            size_t base = (size_t)idxs[row] * D_DIM + c * 32 + kp;
            *(uint4*)&Shi[row][kp] = *(const uint4*)(Bh + base);
            *(uint4*)&Slo[row][kp] = *(const uint4*)(Bl + base);
        }
        __syncthreads();
        {
            short8v ahi[4], bhi[4], bb[4];
            #pragma unroll
            for (int m = 0; m < 4; ++m)
                ahi[m] = *(const short8v*)&Shi[wr * 64 + m * 16 + lr][lq * 8];
            #pragma unroll
            for (int n = 0; n < 4; ++n)
                bhi[n] = *(const short8v*)&Shi[wc * 64 + n * 16 + lr][lq * 8];
            #pragma unroll
            for (int m = 0; m < 4; ++m)
                #pragma unroll
                for (int n = 0; n < 4; ++n)
                    acc[m][n] = __builtin_amdgcn_mfma_f32_16x16x32_bf16(ahi[m], bhi[n], acc[m][n], 0, 0, 0);
            #pragma unroll
            for (int n = 0; n < 4; ++n)             // b-lo pass
                bb[n] = *(const short8v*)&Slo[wc * 64 + n * 16 + lr][lq * 8];
            #pragma unroll
            for (int m = 0; m < 4; ++m)
                #pragma unroll
                for (int n = 0; n < 4; ++n)
                    acc[m][n] = __builtin_amdgcn_mfma_f32_16x16x32_bf16(ahi[m], bb[n], acc[m][n], 0, 0, 0);
            #pragma unroll
            for (int m = 0; m < 4; ++m)             // a-lo pass (reuse bb regs)
                bb[m] = *(const short8v*)&Slo[wr * 64 + m * 16 + lr][lq * 8];
            #pragma unroll
            for (int m = 0; m < 4; ++m)
                #pragma unroll
                for (int n = 0; n < 4; ++n)
                    acc[m][n] = __builtin_amdgcn_mfma_f32_16x16x32_bf16(bb[m], bhi[n], acc[m][n], 0, 0, 0);
        }
        __syncthreads();
    }

    // transform acc -> kernel matrix values (in registers)
    #pragma unroll
    for (int m = 0; m < 4; ++m) {
        #pragma unroll
        for (int r = 0; r < 4; ++r) {
            int i = wr * 64 + m * 16 + lq * 4 + r;
            float ti = ttn[i];
            #pragma unroll
            for (int n = 0; n < 4; ++n) {
                int j = wc * 64 + n * 16 + lr;
                float sq = fmaxf(ti + ttn[j] - 2.0f * acc[m][n][r], 0.0f);
                acc[m][n][r] = av * expf(-sqrtf(sq) * sc);
            }
        }
    }

    // ---- forward rank-4 blocked LDL^T (1 barrier per 4 pivots) ----
    for (int kb = 0; kb < 32; ++kb) {
        const int k0 = kb * 4;
        const int par = kb & 1;
        if (wr == (k0 >> 6) && lq == ((k0 & 15) >> 2)) {   // publish raw rows
            #pragma unroll
            for (int mm = 0; mm < 4; ++mm)
                if (mm == ((k0 >> 4) & 3)) {
                    #pragma unroll
                    for (int n = 0; n < 4; ++n) {
                        int j = wc * 64 + n * 16 + lr;
                        #pragma unroll
                        for (int r = 0; r < 4; ++r)
                            pbuf[par][r][j] = acc[mm][n][r];
                    }
                }
        }
        __syncthreads();
        // uniform 4x4 Crout of diag block
        float B01 = pbuf[par][0][k0+1], B02 = pbuf[par][0][k0+2], B03 = pbuf[par][0][k0+3];
        float d0 = pbuf[par][0][k0], i0 = 1.0f / d0;
        float l10 = pbuf[par][1][k0] * i0;
        float l20 = pbuf[par][2][k0] * i0;
        float l30 = pbuf[par][3][k0] * i0;
        float d1 = pbuf[par][1][k0+1] - l10 * B01, i1 = 1.0f / d1;
        float t12 = pbuf[par][1][k0+2] - l10 * B02;
        float t13 = pbuf[par][1][k0+3] - l10 * B03;
        float l21 = (pbuf[par][2][k0+1] - l20 * B01) * i1;
        float l31 = (pbuf[par][3][k0+1] - l30 * B01) * i1;
        float d2 = pbuf[par][2][k0+2] - l20 * B02 - l21 * t12, i2 = 1.0f / d2;
        float t23 = pbuf[par][2][k0+3] - l20 * B03 - l21 * t13;
        float l32 = (pbuf[par][3][k0+2] - l30 * B02 - l31 * t12) * i2;
        float d3 = pbuf[par][3][k0+3] - l30 * B03 - l31 * t13 - l32 * t23, i3 = 1.0f / d3;
        // rhs forward within block (uniform)
        float fy0 = yLds[k0];
        float fy1 = yLds[k0+1] - l10 * fy0;
        float fy2 = yLds[k0+2] - l20 * fy0 - l21 * fy1;
        float fy3 = yLds[k0+3] - l30 * fy0 - l31 * fy1 - l32 * fy2;
        // cj chains for this thread's 4 cols
        float cj0[4], cj1[4], cj2[4], cj3[4];
        #pragma unroll
        for (int n = 0; n < 4; ++n) {
            int j = wc * 64 + n * 16 + lr;
            float a0 = pbuf[par][0][j];
            float a1 = pbuf[par][1][j] - l10 * a0;
            float a2 = pbuf[par][2][j] - l20 * a0 - l21 * a1;
            float a3 = pbuf[par][3][j] - l30 * a0 - l31 * a1 - l32 * a2;
            cj0[n] = (j > k0)     ? a0 : 0.f;
            cj1[n] = (j > k0 + 1) ? a1 : 0.f;
            cj2[n] = (j > k0 + 2) ? a2 : 0.f;
            cj3[n] = (j > k0 + 3) ? a3 : 0.f;
        }
        // per-row lik chain + rank-4 update
        #pragma unroll
        for (int m = 0; m < 4; ++m) {
            #pragma unroll
            for (int r = 0; r < 4; ++r) {
                int i = wr * 64 + m * 16 + lq * 4 + r;
                float a0 = pbuf[par][0][i];
                float a1 = pbuf[par][1][i] - l10 * a0;
                float a2 = pbuf[par][2][i] - l20 * a0 - l21 * a1;
                float a3 = pbuf[par][3][i] - l30 * a0 - l31 * a1 - l32 * a2;
                float k0v = (i > k0)     ? a0 * i0 : 0.f;
                float k1v = (i > k0 + 1) ? a1 * i1 : 0.f;
                float k2v = (i > k0 + 2) ? a2 * i2 : 0.f;
                float k3v = (i > k0 + 3) ? a3 * i3 : 0.f;
                #pragma unroll
                for (int n = 0; n < 4; ++n) {
                    float t = acc[m][n][r];
                    t = fmaf(-k0v, cj0[n], t);
                    t = fmaf(-k1v, cj1[n], t);
                    t = fmaf(-k2v, cj2[n], t);
                    t = fmaf(-k3v, cj3[n], t);
                    acc[m][n][r] = t;
                }
                if (wc == 0 && lr == 0 && i > k0 + 3) {    // rhs update (8 lanes)
                    float yv = yLds[i];
                    yv = fmaf(-k0v, fy0, yv);
                    yv = fmaf(-k1v, fy1, yv);
                    yv = fmaf(-k2v, fy2, yv);
                    yv = fmaf(-k3v, fy3, yv);
                    yLds[i] = yv;
                }
            }
        }
        if (tid == 0) {
            dvec[k0] = d0; dvec[k0+1] = d1; dvec[k0+2] = d2; dvec[k0+3] = d3;
            yfwd[k0] = fy0; yfwd[k0+1] = fy1; yfwd[k0+2] = fy2; yfwd[k0+3] = fy3;
        }
    }
    __syncthreads();
    if (tid < NN) yLds[tid] = yfwd[tid];     // consolidated forward-solved rhs
    __syncthreads();

    // ---- backward rank-4 (1 barrier per 4 pivots) ----
    for (int kb = 31; kb >= 0; --kb) {
        const int k0 = kb * 4;
        const int par = kb & 1;
        {
            int q = lr - (k0 & 15);
            if (wc == (k0 >> 6) && q >= 0 && q < 4) {      // publish factored cols
                #pragma unroll
                for (int nn = 0; nn < 4; ++nn)
                    if (nn == ((k0 >> 4) & 3)) {
                        #pragma unroll
                        for (int m = 0; m < 4; ++m)
                            #pragma unroll
                            for (int r = 0; r < 4; ++r)
                                pbuf[par][q][wr * 64 + m * 16 + lq * 4 + r] = acc[m][nn][r];
                    }
            }
        }
        __syncthreads();
        float w3 = yLds[k0+3] / dvec[k0+3];
        float w2 = (yLds[k0+2] - pbuf[par][3][k0+2] * w3) / dvec[k0+2];
        float w1 = (yLds[k0+1] - pbuf[par][2][k0+1] * w2 - pbuf[par][3][k0+1] * w3) / dvec[k0+1];
        float w0 = (yLds[k0]   - pbuf[par][1][k0] * w1 - pbuf[par][2][k0] * w2
                               - pbuf[par][3][k0] * w3) / dvec[k0];
        if (tid == 0) { wvec[k0] = w0; wvec[k0+1] = w1; wvec[k0+2] = w2; wvec[k0+3] = w3; }
        if (tid < k0) {
            float yv = yLds[tid];
            yv = fmaf(-pbuf[par][0][tid], w0, yv);
            yv = fmaf(-pbuf[par][1][tid], w1, yv);
            yv = fmaf(-pbuf[par][2][tid], w2, yv);
            yv = fmaf(-pbuf[par][3][tid], w3, yv);
            yLds[tid] = yv;
        }
    }
    __syncthreads();

    float p1 = 0.f, p2 = 0.f;
    if (tid < NN) {
        float w = wvec[tid];
        float nyv = trainy[idxs[tid]] + 0.01f * noise[(size_t)b * NN + tid] - ymean;
        p1 = w * nyv;
        p2 = w * c0v[tid];
    }
    for (int off = 32; off; off >>= 1) {
        p1 += __shfl_down(p1, off, 64);
        p2 += __shfl_down(p2, off, 64);
    }
    if ((tid & 63) == 0) { red[wv * 2] = p1; red[wv * 2 + 1] = p2; }
    __syncthreads();
    if (tid == 0) {
        out[b]        = (red[0] + red[2] + red[4] + red[6]) + ymean;
        out[B_SZ + b] = av - (red[1] + red[3] + red[5] + red[7]);
    }
}

extern "C" void kernel_launch(void* const* d_in, const int* in_sizes, int n_in,
                              void* d_out, int out_size, void* d_ws, size_t ws_size,
                              hipStream_t stream) {
    const float* x      = (const float*)d_in[0];
    const float* trainX = (const float*)d_in[1];
    const float* trainy = (const float*)d_in[2];
    const float* noise  = (const float*)d_in[3];
    const float* lp     = (const float*)d_in[4];
    const float* ap     = (const float*)d_in[5];
    const float* ymp    = (const float*)d_in[6];
    float* out = (float*)d_out;

    char* ws = (char*)d_ws;
    size_t off = 0;
    auto alloc = [&](size_t bytes) {
        void* p = ws + off;
        off = (off + bytes + 255) & ~(size_t)255;
        return p;
    };
    float* tt   = (float*)alloc((size_t)N_TRAIN * 4);
    float* xx   = (float*)alloc((size_t)B_SZ * 4);
    int*   nidb = (int*)  alloc((size_t)B_SZ * NN * 4);
    float* nsqb = (float*)alloc((size_t)B_SZ * NN * 4);
    int*   cand = (int*)  alloc((size_t)B_SZ * KSEL * 4);
    u16*   Ah   = (u16*)  alloc((size_t)B_SZ * D_DIM * 2);
    u16*   Bh   = (u16*)  alloc((size_t)N_TRAIN * D_DIM * 2);
    u16*   Bl   = (u16*)  alloc((size_t)N_TRAIN * D_DIM * 2);
    size_t distBytes = (ws_size > off) ? (ws_size - off) : 0;
    u16* distu = (u16*)(ws + off);
    int R = (int)(distBytes / ((size_t)N_PAD * 2));
    if (R > B_SZ) R = B_SZ;      // single chunk if ws allows (k2 occupancy 4/CU)
    if (R < 1) R = 1;

    {
        int waves = N_TRAIN + B_SZ;
        k0_norms<<<(waves + 3) / 4, 256, 0, stream>>>(trainX, x, tt, xx);
    }
    kcv2<<<4096, 256, 0, stream>>>(trainX, Bh, Bl, N_TRAIN * D_DIM / 4);
    kcv<<<256, 256, 0, stream>>>(x, Ah, B_SZ * D_DIM / 4);

    for (int r0 = 0; r0 < B_SZ; r0 += R) {
        int rc = (B_SZ - r0 < R) ? (B_SZ - r0) : R;
        dim3 g1((N_TRAIN + 127) / 128, (rc + 127) / 128);
        k1m<<<g1, 256, 0, stream>>>(Ah, Bh, xx, tt, distu, r0, rc);
        k2_select<<<rc, 256, 0, stream>>>(distu, r0, cand);
    }
    k2m<<<B_SZ, 256, 0, stream>>>(x, trainX, xx, tt, cand, nidb, nsqb);
    k3_solve<<<B_SZ, 256, 0, stream>>>(Bh, Bl, trainy, noise, tt, nidb, nsqb,
                                       lp, ap, ymp, out);
}